// Round 3
// baseline (2709.304 us; speedup 1.0000x reference)
//
#include <hip/hip_runtime.h>

// Branch table: op = m*3+c -> branch index
// branches: 0=agg(h) 1=h 2=h_in 3=s1 4=agg(s1) 5=s2 6=agg(s2)
static __device__ const int BRTAB[18] = {0,1,2, 0,1,2, 4,3,2, 0,1,2, 4,3,2, 6,5,2};

struct OpList  { int ops[9]; };
struct MixList { const float* X[9]; int op[9]; int nops; };

__device__ __forceinline__ float4 f4fma(float a, float4 b, float4 c) {
  c.x = fmaf(a, b.x, c.x); c.y = fmaf(a, b.y, c.y);
  c.z = fmaf(a, b.z, c.z); c.w = fmaf(a, b.w, c.w);
  return c;
}

// ---- 1) degree histogram ----
__global__ void k_hist(const int* __restrict__ dst, int* __restrict__ deg, int E) {
  int e = blockIdx.x * 256 + threadIdx.x;
  if (e < E) atomicAdd(&deg[dst[e]], 1);
}

// ---- 2) exclusive prefix-sum over degrees (single block, shfl scan) ----
__global__ __launch_bounds__(1024) void k_scan(
    const int* __restrict__ deg, int* __restrict__ off, int* __restrict__ cur,
    float* __restrict__ inv_deg, int n) {
  __shared__ int wsum[16];
  const int t = threadIdx.x, lane = t & 63, wid = t >> 6;
  int running = 0;
  for (int base = 0; base < n; base += 1024) {
    __syncthreads();  // protect wsum from previous iteration
    int i = base + t;
    int v = (i < n) ? deg[i] : 0;
    int x = v;
#pragma unroll
    for (int s = 1; s < 64; s <<= 1) {
      int u = __shfl_up(x, (unsigned)s, 64);
      if (lane >= s) x += u;
    }
    if (lane == 63) wsum[wid] = x;
    __syncthreads();
    if (t < 16) {
      int w = wsum[t];
#pragma unroll
      for (int s = 1; s < 16; s <<= 1) {
        int u = __shfl_up(w, (unsigned)s, 16);
        if (t >= s) w += u;
      }
      wsum[t] = w;
    }
    __syncthreads();
    int excl = running + x + ((wid > 0) ? wsum[wid - 1] : 0) - v;
    if (i < n) {
      off[i] = excl; cur[i] = excl;
      inv_deg[i] = 1.0f / fmaxf((float)v, 1.0f);
    }
    running += wsum[15];
  }
  if (t == 0) off[n] = running;
}

// ---- 3) bucket edges by dst ----
__global__ void k_scatter(const int* __restrict__ src, const int* __restrict__ dst,
                          int* __restrict__ cur, int* __restrict__ csr, int E) {
  int e = blockIdx.x * 256 + threadIdx.x;
  if (e < E) {
    int pos = atomicAdd(&cur[dst[e]], 1);
    csr[pos] = src[e];
  }
}

// ---- 4) mean aggregation: one wave per node, float2 per lane ----
__global__ void k_agg(const float* __restrict__ x, const int* __restrict__ csr,
                      const int* __restrict__ off, const float* __restrict__ inv_deg,
                      float* __restrict__ outb, int n) {
  int node = blockIdx.x * 4 + (threadIdx.x >> 6);
  int lane = threadIdx.x & 63;
  if (node >= n) return;
  int e0 = off[node], e1 = off[node + 1];
  const float2* xp = (const float2*)x;
  float ax = 0.f, ay = 0.f;
  for (int e = e0; e < e1; ++e) {
    int s = csr[e];
    float2 v = xp[(size_t)s * 64 + lane];
    ax += v.x; ay += v.y;
  }
  float iv = inv_deg[node];
  float2 r; r.x = ax * iv; r.y = ay * iv;
  ((float2*)outb)[(size_t)node * 64 + lane] = r;
}

// ---- 5) per-branch raw second-moment partials (128 rows/block, 2 LDS stages) ----
__global__ __launch_bounds__(256) void k_stats_part(
    const float* __restrict__ X, float* __restrict__ Spart,
    float* __restrict__ mupart, int n) {
  __shared__ float Xs[64][128];
  const int t = threadIdx.x;
  const int base = blockIdx.x * 128;
  const int a = t >> 4, b = t & 15;
  float accS[8][8];
#pragma unroll
  for (int i = 0; i < 8; ++i)
#pragma unroll
    for (int j = 0; j < 8; ++j) accS[i][j] = 0.f;
  float mus = 0.f;
  for (int st = 0; st < 2; ++st) {
    __syncthreads();
    const float4* X4 = (const float4*)X;
#pragma unroll
    for (int i = 0; i < 8; ++i) {
      int f = t + i * 256;
      int r = f >> 5, c4 = f & 31;
      int row = base + st * 64 + r;
      float4 v = make_float4(0.f, 0.f, 0.f, 0.f);
      if (row < n) v = X4[(size_t)row * 32 + c4];
      *(float4*)&Xs[r][c4 * 4] = v;
    }
    __syncthreads();
    for (int r = 0; r < 64; ++r) {
      float xa[8], xb[8];
      *(float4*)&xa[0] = *(float4*)&Xs[r][a * 8];
      *(float4*)&xa[4] = *(float4*)&Xs[r][a * 8 + 4];
      *(float4*)&xb[0] = *(float4*)&Xs[r][b * 8];
      *(float4*)&xb[4] = *(float4*)&Xs[r][b * 8 + 4];
#pragma unroll
      for (int i = 0; i < 8; ++i)
#pragma unroll
        for (int j = 0; j < 8; ++j)
          accS[i][j] = fmaf(xa[i], xb[j], accS[i][j]);
    }
    if (t < 128) {
      for (int r = 0; r < 64; ++r) mus += Xs[r][t];
    }
  }
  float* Sp = Spart + (size_t)blockIdx.x * 16384;
#pragma unroll
  for (int i = 0; i < 8; ++i) {
    float4 v0 = make_float4(accS[i][0], accS[i][1], accS[i][2], accS[i][3]);
    float4 v1 = make_float4(accS[i][4], accS[i][5], accS[i][6], accS[i][7]);
    *(float4*)&Sp[(a * 8 + i) * 128 + b * 8]     = v0;
    *(float4*)&Sp[(a * 8 + i) * 128 + b * 8 + 4] = v1;
  }
  if (t < 128) mupart[blockIdx.x * 128 + t] = mus;
}

// ---- 6) reduce stat partials ----
__global__ void k_stats_reduce(const float* __restrict__ Spart,
                               const float* __restrict__ mupart,
                               float* __restrict__ S, float* __restrict__ mus,
                               int nblk) {
  int i = blockIdx.x * 256 + threadIdx.x;
  float s = 0.f;
  for (int bb = 0; bb < nblk; ++bb) s += Spart[(size_t)bb * 16384 + i];
  S[i] = s;
  if (i < 128) {
    float m = 0.f;
    for (int bb = 0; bb < nblk; ++bb) m += mupart[bb * 128 + i];
    mus[i] = m;
  }
}

// ---- 7) U[op] = W[op] @ S[br(op)]  (for var_z = diag(W S W^T)) ----
__global__ __launch_bounds__(256) void k_varU(
    const float* __restrict__ Wall, const float* __restrict__ Sall,
    float* __restrict__ U, OpList ol) {
  const int op = ol.ops[blockIdx.y];
  const int br = BRTAB[op];
  const float* A = Wall + (size_t)op * 16384;
  const float* B = Sall + (size_t)br * 16384;
  const int d0 = blockIdx.x * 64;
  __shared__ float As[64][32];
  __shared__ float Bs[32][128];
  const int t = threadIdx.x, tr = t >> 5, tc = t & 31;
  float4 acc[8];
#pragma unroll
  for (int i = 0; i < 8; ++i) acc[i] = make_float4(0.f, 0.f, 0.f, 0.f);
  for (int kc = 0; kc < 4; ++kc) {
    const int k0 = kc * 32;
    __syncthreads();
#pragma unroll
    for (int i = 0; i < 2; ++i) {
      int f = t + i * 256;
      int r = f >> 3, kq = f & 7;
      *(float4*)&As[r][kq * 4] = *(const float4*)&A[(d0 + r) * 128 + k0 + kq * 4];
    }
#pragma unroll
    for (int i = 0; i < 4; ++i) {
      int f = t + i * 256;
      int k = f >> 5, c4 = f & 31;
      *(float4*)&Bs[k][c4 * 4] = *(const float4*)&B[(k0 + k) * 128 + c4 * 4];
    }
    __syncthreads();
#pragma unroll
    for (int kq = 0; kq < 8; ++kq) {
      float4 b0 = *(float4*)&Bs[kq * 4 + 0][tc * 4];
      float4 b1 = *(float4*)&Bs[kq * 4 + 1][tc * 4];
      float4 b2 = *(float4*)&Bs[kq * 4 + 2][tc * 4];
      float4 b3 = *(float4*)&Bs[kq * 4 + 3][tc * 4];
#pragma unroll
      for (int i = 0; i < 8; ++i) {
        float4 av = *(float4*)&As[tr * 8 + i][kq * 4];
        acc[i] = f4fma(av.x, b0, acc[i]);
        acc[i] = f4fma(av.y, b1, acc[i]);
        acc[i] = f4fma(av.z, b2, acc[i]);
        acc[i] = f4fma(av.w, b3, acc[i]);
      }
    }
  }
#pragma unroll
  for (int i = 0; i < 8; ++i)
    *(float4*)&U[(size_t)op * 16384 + (d0 + tr * 8 + i) * 128 + tc * 4] = acc[i];
}

// ---- 8) finalize BN fold: scale = g/sqrt(var+eps), shift = beta - mean0*scale ----
// (linear bias b cancels exactly in training-mode BN)
__global__ void k_bnfinal(OpList ol, const float* __restrict__ Wall,
                          const float* __restrict__ U, const float* __restrict__ mus,
                          const float* __restrict__ gamma, const float* __restrict__ beta,
                          float* __restrict__ scale, float* __restrict__ shift, int n) {
  const int op = ol.ops[blockIdx.x];
  const int br = BRTAB[op];
  const int d = threadIdx.x;
  __shared__ __align__(16) float muL[128];
  const float invN = 1.0f / (float)n;
  muL[d] = mus[br * 128 + d] * invN;
  __syncthreads();
  const float4* Wr = (const float4*)(Wall + (size_t)op * 16384 + d * 128);
  const float4* Ur = (const float4*)(U + (size_t)op * 16384 + d * 128);
  const float4* m4 = (const float4*)muL;
  float q = 0.f, mz = 0.f;
#pragma unroll 8
  for (int j = 0; j < 32; ++j) {
    float4 w = Wr[j], u = Ur[j], m = m4[j];
    q  += w.x * u.x + w.y * u.y + w.z * u.z + w.w * u.w;
    mz += w.x * m.x + w.y * m.y + w.z * m.z + w.w * m.w;
  }
  float var = fmaxf(q * invN - mz * mz, 0.0f);
  float is = 1.0f / sqrtf(var + 1e-5f);
  float scl = gamma[op * 128 + d] * is;
  scale[op * 128 + d] = scl;
  shift[op * 128 + d] = beta[op * 128 + d] - mz * scl;
}

// ---- 9) fused multi-op GEMM + BN + ReLU + weighted accumulate ----
// block: 64 rows x 128 cols, 256 thr, thread tile 8x4 (f32, FMA-bound)
__global__ __launch_bounds__(256) void k_mix(
    MixList ml, const float* __restrict__ Wall, const float* __restrict__ scale,
    const float* __restrict__ shift, const float* __restrict__ wts,
    float* __restrict__ outb, int n) {
  __shared__ float Xs[64][32];
  __shared__ float Wt[32][128];  // W transposed in LDS: Wt[k][c] = W[c][k]
  const int t = threadIdx.x, tr = t >> 5, tc = t & 31;
  const int row0 = blockIdx.x * 64;
  float4 oacc[8];
#pragma unroll
  for (int i = 0; i < 8; ++i) oacc[i] = make_float4(0.f, 0.f, 0.f, 0.f);
  for (int o = 0; o < ml.nops; ++o) {
    const float* X = ml.X[o];
    const int op = ml.op[o];
    const float* Wp = Wall + (size_t)op * 16384;
    float4 acc[8];
#pragma unroll
    for (int i = 0; i < 8; ++i) acc[i] = make_float4(0.f, 0.f, 0.f, 0.f);
    for (int kc = 0; kc < 4; ++kc) {
      const int k0 = kc * 32;
      __syncthreads();  // protect LDS reuse across chunks/ops
#pragma unroll
      for (int i = 0; i < 2; ++i) {
        int f = t + i * 256;
        int r = f >> 3, kq = f & 7;
        int row = row0 + r;
        float4 v = make_float4(0.f, 0.f, 0.f, 0.f);
        if (row < n) v = *(const float4*)&X[(size_t)row * 128 + k0 + kq * 4];
        *(float4*)&Xs[r][kq * 4] = v;
      }
#pragma unroll
      for (int i = 0; i < 4; ++i) {
        int f = t + i * 256;
        int c = f >> 3, kq = f & 7;
        float4 v = *(const float4*)&Wp[c * 128 + k0 + kq * 4];
        Wt[kq * 4 + 0][c] = v.x;
        Wt[kq * 4 + 1][c] = v.y;
        Wt[kq * 4 + 2][c] = v.z;
        Wt[kq * 4 + 3][c] = v.w;
      }
      __syncthreads();
#pragma unroll
      for (int kq = 0; kq < 8; ++kq) {
        float4 w0 = *(float4*)&Wt[kq * 4 + 0][tc * 4];
        float4 w1 = *(float4*)&Wt[kq * 4 + 1][tc * 4];
        float4 w2 = *(float4*)&Wt[kq * 4 + 2][tc * 4];
        float4 w3 = *(float4*)&Wt[kq * 4 + 3][tc * 4];
#pragma unroll
        for (int i = 0; i < 8; ++i) {
          float4 xv = *(float4*)&Xs[tr * 8 + i][kq * 4];
          acc[i] = f4fma(xv.x, w0, acc[i]);
          acc[i] = f4fma(xv.y, w1, acc[i]);
          acc[i] = f4fma(xv.z, w2, acc[i]);
          acc[i] = f4fma(xv.w, w3, acc[i]);
        }
      }
    }
    float4 sc = *(const float4*)&scale[op * 128 + tc * 4];
    float4 sh = *(const float4*)&shift[op * 128 + tc * 4];
    float wgt = wts[op];
#pragma unroll
    for (int i = 0; i < 8; ++i) {
      float4 y;
      y.x = fmaxf(fmaf(acc[i].x, sc.x, sh.x), 0.f);
      y.y = fmaxf(fmaf(acc[i].y, sc.y, sh.y), 0.f);
      y.z = fmaxf(fmaf(acc[i].z, sc.z, sh.z), 0.f);
      y.w = fmaxf(fmaf(acc[i].w, sc.w, sh.w), 0.f);
      oacc[i].x = fmaf(wgt, y.x, oacc[i].x);
      oacc[i].y = fmaf(wgt, y.y, oacc[i].y);
      oacc[i].z = fmaf(wgt, y.z, oacc[i].z);
      oacc[i].w = fmaf(wgt, y.w, oacc[i].w);
    }
  }
#pragma unroll
  for (int i = 0; i < 8; ++i) {
    int row = row0 + tr * 8 + i;
    if (row < n) *(float4*)&outb[(size_t)row * 128 + tc * 4] = oacc[i];
  }
}

extern "C" void kernel_launch(void* const* d_in, const int* in_sizes, int n_in,
                              void* d_out, int out_size, void* d_ws, size_t ws_size,
                              hipStream_t stream) {
  (void)n_in; (void)out_size; (void)ws_size;
  const int*   edge  = (const int*)d_in[0];
  const float* h     = (const float*)d_in[1];
  const float* h_in  = (const float*)d_in[2];
  const float* wts   = (const float*)d_in[3];
  const float* W     = (const float*)d_in[4];
  // d_in[5] = b : cancels exactly in training-mode BN, unused
  const float* gamma = (const float*)d_in[6];
  const float* beta  = (const float*)d_in[7];
  float* out = (float*)d_out;

  const int E = in_sizes[0] / 2;
  const int N = in_sizes[1] / 128;
  const int* src = edge;
  const int* dst = edge + E;

  char* ws = (char*)d_ws;
  size_t off = 0;
  auto carve = [&](size_t bytes) -> void* {
    void* p = ws + off;
    off += (bytes + 511) & ~((size_t)511);
    return p;
  };
  int*   degw   = (int*)carve((size_t)N * 4);
  int*   offw   = (int*)carve((size_t)(N + 1) * 4);
  int*   curw   = (int*)carve((size_t)N * 4);
  int*   csrw   = (int*)carve((size_t)E * 4);
  float* invw   = (float*)carve((size_t)N * 4);
  float* Ssum   = (float*)carve((size_t)7 * 16384 * 4);
  float* musum  = (float*)carve((size_t)7 * 128 * 4);
  float* U      = (float*)carve((size_t)18 * 16384 * 4);
  float* scl    = (float*)carve((size_t)18 * 128 * 4);
  float* shf    = (float*)carve((size_t)18 * 128 * 4);
  const int nblk = (N + 127) / 128;
  float* Spart  = (float*)carve((size_t)nblk * 16384 * 4);
  float* mupart = (float*)carve((size_t)nblk * 128 * 4);
  float* agg0   = (float*)carve((size_t)N * 128 * 4);
  float* agg1   = (float*)carve((size_t)N * 128 * 4);
  float* agg2   = (float*)carve((size_t)N * 128 * 4);

  float* s1 = out;
  float* s2 = out + (size_t)N * 128;
  float* s3 = out + (size_t)2 * N * 128;

  hipMemsetAsync(degw, 0, (size_t)N * 4, stream);
  const int gE   = (E + 255) / 256;
  const int gAgg = (N + 3) / 4;
  const int gMix = (N + 63) / 64;

  k_hist<<<gE, 256, 0, stream>>>(dst, degw, E);
  k_scan<<<1, 1024, 0, stream>>>(degw, offw, curw, invw, N);
  k_scatter<<<gE, 256, 0, stream>>>(src, dst, curw, csrw, E);
  k_agg<<<gAgg, 256, 0, stream>>>(h, csrw, offw, invw, agg0, N);

  auto stats = [&](const float* X, int slot) {
    k_stats_part<<<nblk, 256, 0, stream>>>(X, Spart, mupart, N);
    k_stats_reduce<<<64, 256, 0, stream>>>(Spart, mupart,
        Ssum + (size_t)slot * 16384, musum + (size_t)slot * 128, nblk);
  };

  // ---- stage 1 ----
  stats(agg0, 0); stats(h, 1); stats(h_in, 2);
  OpList pa{}; { int v[9] = {0,1,2,3,4,5,9,10,11}; for (int i = 0; i < 9; ++i) pa.ops[i] = v[i]; }
  k_varU<<<dim3(2, 9), 256, 0, stream>>>(W, Ssum, U, pa);
  k_bnfinal<<<9, 128, 0, stream>>>(pa, W, U, musum, gamma, beta, scl, shf, N);
  MixList m1{}; m1.nops = 3;
  m1.X[0] = agg0; m1.op[0] = 0; m1.X[1] = h; m1.op[1] = 1; m1.X[2] = h_in; m1.op[2] = 2;
  k_mix<<<gMix, 256, 0, stream>>>(m1, W, scl, shf, wts, s1, N);

  // ---- stage 2 ----
  k_agg<<<gAgg, 256, 0, stream>>>(s1, csrw, offw, invw, agg1, N);
  stats(s1, 3); stats(agg1, 4);
  OpList pb{}; { int v[6] = {6,7,8,12,13,14}; for (int i = 0; i < 6; ++i) pb.ops[i] = v[i]; }
  k_varU<<<dim3(2, 6), 256, 0, stream>>>(W, Ssum, U, pb);
  k_bnfinal<<<6, 128, 0, stream>>>(pb, W, U, musum, gamma, beta, scl, shf, N);
  MixList m2{}; m2.nops = 6;
  m2.X[0] = agg0; m2.op[0] = 3; m2.X[1] = h;  m2.op[1] = 4; m2.X[2] = h_in; m2.op[2] = 5;
  m2.X[3] = agg1; m2.op[3] = 6; m2.X[4] = s1; m2.op[4] = 7; m2.X[5] = h_in; m2.op[5] = 8;
  k_mix<<<gMix, 256, 0, stream>>>(m2, W, scl, shf, wts, s2, N);

  // ---- stage 3 ----
  k_agg<<<gAgg, 256, 0, stream>>>(s2, csrw, offw, invw, agg2, N);
  stats(s2, 5); stats(agg2, 6);
  OpList pc{}; { int v[3] = {15,16,17}; for (int i = 0; i < 3; ++i) pc.ops[i] = v[i]; }
  k_varU<<<dim3(2, 3), 256, 0, stream>>>(W, Ssum, U, pc);
  k_bnfinal<<<3, 128, 0, stream>>>(pc, W, U, musum, gamma, beta, scl, shf, N);
  MixList m3{}; m3.nops = 9;
  m3.X[0] = agg0; m3.op[0] = 9;  m3.X[1] = h;  m3.op[1] = 10; m3.X[2] = h_in; m3.op[2] = 11;
  m3.X[3] = agg1; m3.op[3] = 12; m3.X[4] = s1; m3.op[4] = 13; m3.X[5] = h_in; m3.op[5] = 14;
  m3.X[6] = agg2; m3.op[6] = 15; m3.X[7] = s2; m3.op[7] = 16; m3.X[8] = h_in; m3.op[8] = 17;
  k_mix<<<gMix, 256, 0, stream>>>(m3, W, scl, shf, wts, s3, N);
}

// Round 4
// 1802.761 us; speedup vs baseline: 1.5029x; 1.5029x over previous
//
#include <hip/hip_runtime.h>
#include <hip/hip_fp16.h>

// branches: 0=agg(h) 1=h 2=h_in 3=s1 4=agg(s1) 5=s2 6=agg(s2)
static __device__ const int BRTAB[18] = {0,1,2, 0,1,2, 4,3,2, 0,1,2, 4,3,2, 6,5,2};

struct OpList   { int ops[9]; };
struct MixListH { const _Float16* X[9]; int op[9]; int nops; };

using half8 = __attribute__((ext_vector_type(8))) _Float16;
using half4 = __attribute__((ext_vector_type(4))) _Float16;
using f32x4 = __attribute__((ext_vector_type(4))) float;
using s16x8 = __attribute__((ext_vector_type(8))) short;

__device__ __forceinline__ float4 f4fma(float a, float4 b, float4 c) {
  c.x = fmaf(a, b.x, c.x); c.y = fmaf(a, b.y, c.y);
  c.z = fmaf(a, b.z, c.z); c.w = fmaf(a, b.w, c.w);
  return c;
}

// ---- fp32 -> fp16 conversion (grid-stride, float4 -> half4) ----
__global__ void k_f2h(const float* __restrict__ x, _Float16* __restrict__ y, int n4) {
  for (int i = blockIdx.x * 256 + threadIdx.x; i < n4; i += gridDim.x * 256) {
    float4 v = ((const float4*)x)[i];
    half4 o = { (_Float16)v.x, (_Float16)v.y, (_Float16)v.z, (_Float16)v.w };
    ((half4*)y)[i] = o;
  }
}

// ---- degree histogram ----
__global__ void k_hist(const int* __restrict__ dst, int* __restrict__ deg, int E) {
  int e = blockIdx.x * 256 + threadIdx.x;
  if (e < E) atomicAdd(&deg[dst[e]], 1);
}

// ---- exclusive prefix-sum over degrees (single block) ----
__global__ __launch_bounds__(1024) void k_scan(
    const int* __restrict__ deg, int* __restrict__ off, int* __restrict__ cur,
    float* __restrict__ inv_deg, int n) {
  __shared__ int wsum[16];
  const int t = threadIdx.x, lane = t & 63, wid = t >> 6;
  int running = 0;
  for (int base = 0; base < n; base += 1024) {
    __syncthreads();
    int i = base + t;
    int v = (i < n) ? deg[i] : 0;
    int x = v;
#pragma unroll
    for (int s = 1; s < 64; s <<= 1) {
      int u = __shfl_up(x, (unsigned)s, 64);
      if (lane >= s) x += u;
    }
    if (lane == 63) wsum[wid] = x;
    __syncthreads();
    if (t < 16) {
      int w = wsum[t];
#pragma unroll
      for (int s = 1; s < 16; s <<= 1) {
        int u = __shfl_up(w, (unsigned)s, 16);
        if (t >= s) w += u;
      }
      wsum[t] = w;
    }
    __syncthreads();
    int excl = running + x + ((wid > 0) ? wsum[wid - 1] : 0) - v;
    if (i < n) {
      off[i] = excl; cur[i] = excl;
      inv_deg[i] = 1.0f / fmaxf((float)v, 1.0f);
    }
    running += wsum[15];
  }
  if (t == 0) off[n] = running;
}

// ---- bucket edges by dst ----
__global__ void k_scatter(const int* __restrict__ src, const int* __restrict__ dst,
                          int* __restrict__ cur, int* __restrict__ csr, int E) {
  int e = blockIdx.x * 256 + threadIdx.x;
  if (e < E) {
    int pos = atomicAdd(&cur[dst[e]], 1);
    csr[pos] = src[e];
  }
}

// ---- mean aggregation: one wave per node, fp16 gather, f32 accum, fp16 out ----
__global__ void k_agg(const _Float16* __restrict__ x, const int* __restrict__ csr,
                      const int* __restrict__ off, const float* __restrict__ inv_deg,
                      _Float16* __restrict__ outb, int n) {
  int node = blockIdx.x * 4 + (threadIdx.x >> 6);
  int lane = threadIdx.x & 63;
  if (node >= n) return;
  int e0 = off[node], e1 = off[node + 1];
  const __half2* xp = (const __half2*)x;
  float ax = 0.f, ay = 0.f;
  for (int e = e0; e < e1; ++e) {
    int s = csr[e];
    float2 v = __half22float2(xp[(size_t)s * 64 + lane]);
    ax += v.x; ay += v.y;
  }
  float iv = inv_deg[node];
  ((__half2*)outb)[(size_t)node * 64 + lane] = __floats2half2_rn(ax * iv, ay * iv);
}

// ---- second moments + column sums: 256 rows/block, atomicAdd into S ----
__global__ __launch_bounds__(256) void k_stats_part(
    const _Float16* __restrict__ X, float* __restrict__ S,
    float* __restrict__ mus, int n) {
  __shared__ float Xs[64][128];
  const int t = threadIdx.x;
  const int base = blockIdx.x * 256;
  const int a = t >> 4, b = t & 15;
  float accS[8][8];
#pragma unroll
  for (int i = 0; i < 8; ++i)
#pragma unroll
    for (int j = 0; j < 8; ++j) accS[i][j] = 0.f;
  float muacc = 0.f;
  for (int st = 0; st < 4; ++st) {
    __syncthreads();
#pragma unroll
    for (int i = 0; i < 4; ++i) {
      int f = t + i * 256;           // 1024 chunks of 8 halves (64 rows x 16)
      int r = f >> 4, c8 = f & 15;
      int row = base + st * 64 + r;
      float4 lo = make_float4(0.f, 0.f, 0.f, 0.f);
      float4 hi = make_float4(0.f, 0.f, 0.f, 0.f);
      if (row < n) {
        union { s16x8 s; _Float16 f16[8]; } u;
        u.s = *(const s16x8*)(X + (size_t)row * 128 + c8 * 8);
        lo = make_float4((float)u.f16[0], (float)u.f16[1], (float)u.f16[2], (float)u.f16[3]);
        hi = make_float4((float)u.f16[4], (float)u.f16[5], (float)u.f16[6], (float)u.f16[7]);
      }
      *(float4*)&Xs[r][c8 * 8]     = lo;
      *(float4*)&Xs[r][c8 * 8 + 4] = hi;
    }
    __syncthreads();
    for (int r = 0; r < 64; ++r) {
      float xa[8], xb[8];
      *(float4*)&xa[0] = *(float4*)&Xs[r][a * 8];
      *(float4*)&xa[4] = *(float4*)&Xs[r][a * 8 + 4];
      *(float4*)&xb[0] = *(float4*)&Xs[r][b * 8];
      *(float4*)&xb[4] = *(float4*)&Xs[r][b * 8 + 4];
#pragma unroll
      for (int i = 0; i < 8; ++i)
#pragma unroll
        for (int j = 0; j < 8; ++j)
          accS[i][j] = fmaf(xa[i], xb[j], accS[i][j]);
    }
    if (t < 128) {
      for (int r = 0; r < 64; ++r) muacc += Xs[r][t];
    }
  }
#pragma unroll
  for (int i = 0; i < 8; ++i)
#pragma unroll
    for (int j = 0; j < 8; ++j)
      atomicAdd(&S[(a * 8 + i) * 128 + b * 8 + j], accS[i][j]);
  if (t < 128) atomicAdd(&mus[t], muacc);
}

// ---- U[op] = W[op] @ S[br(op)] ----
__global__ __launch_bounds__(256) void k_varU(
    const float* __restrict__ Wall, const float* __restrict__ Sall,
    float* __restrict__ U, OpList ol) {
  const int op = ol.ops[blockIdx.y];
  const int br = BRTAB[op];
  const float* A = Wall + (size_t)op * 16384;
  const float* B = Sall + (size_t)br * 16384;
  const int d0 = blockIdx.x * 64;
  __shared__ float As[64][32];
  __shared__ float Bs[32][128];
  const int t = threadIdx.x, tr = t >> 5, tc = t & 31;
  float4 acc[8];
#pragma unroll
  for (int i = 0; i < 8; ++i) acc[i] = make_float4(0.f, 0.f, 0.f, 0.f);
  for (int kc = 0; kc < 4; ++kc) {
    const int k0 = kc * 32;
    __syncthreads();
#pragma unroll
    for (int i = 0; i < 2; ++i) {
      int f = t + i * 256;
      int r = f >> 3, kq = f & 7;
      *(float4*)&As[r][kq * 4] = *(const float4*)&A[(d0 + r) * 128 + k0 + kq * 4];
    }
#pragma unroll
    for (int i = 0; i < 4; ++i) {
      int f = t + i * 256;
      int k = f >> 5, c4 = f & 31;
      *(float4*)&Bs[k][c4 * 4] = *(const float4*)&B[(k0 + k) * 128 + c4 * 4];
    }
    __syncthreads();
#pragma unroll
    for (int kq = 0; kq < 8; ++kq) {
      float4 b0 = *(float4*)&Bs[kq * 4 + 0][tc * 4];
      float4 b1 = *(float4*)&Bs[kq * 4 + 1][tc * 4];
      float4 b2 = *(float4*)&Bs[kq * 4 + 2][tc * 4];
      float4 b3 = *(float4*)&Bs[kq * 4 + 3][tc * 4];
#pragma unroll
      for (int i = 0; i < 8; ++i) {
        float4 av = *(float4*)&As[tr * 8 + i][kq * 4];
        acc[i] = f4fma(av.x, b0, acc[i]);
        acc[i] = f4fma(av.y, b1, acc[i]);
        acc[i] = f4fma(av.z, b2, acc[i]);
        acc[i] = f4fma(av.w, b3, acc[i]);
      }
    }
  }
#pragma unroll
  for (int i = 0; i < 8; ++i)
    *(float4*)&U[(size_t)op * 16384 + (d0 + tr * 8 + i) * 128 + tc * 4] = acc[i];
}

// ---- BN fold: scale = g*rsqrt(var+eps), shift = beta - mean_z*scale ----
__global__ void k_bnfinal(OpList ol, const float* __restrict__ Wall,
                          const float* __restrict__ U, const float* __restrict__ mus,
                          const float* __restrict__ gamma, const float* __restrict__ beta,
                          float* __restrict__ scale, float* __restrict__ shift, int n) {
  const int op = ol.ops[blockIdx.x];
  const int br = BRTAB[op];
  const int d = threadIdx.x;
  __shared__ __align__(16) float muL[128];
  const float invN = 1.0f / (float)n;
  muL[d] = mus[br * 128 + d] * invN;
  __syncthreads();
  const float4* Wr = (const float4*)(Wall + (size_t)op * 16384 + d * 128);
  const float4* Ur = (const float4*)(U + (size_t)op * 16384 + d * 128);
  const float4* m4 = (const float4*)muL;
  float q = 0.f, mz = 0.f;
#pragma unroll 8
  for (int j = 0; j < 32; ++j) {
    float4 w = Wr[j], u = Ur[j], m = m4[j];
    q  += w.x * u.x + w.y * u.y + w.z * u.z + w.w * u.w;
    mz += w.x * m.x + w.y * m.y + w.z * m.z + w.w * m.w;
  }
  float var = fmaxf(q * invN - mz * mz, 0.0f);
  float is = 1.0f / sqrtf(var + 1e-5f);
  float scl = gamma[op * 128 + d] * is;
  scale[op * 128 + d] = scl;
  shift[op * 128 + d] = beta[op * 128 + d] - mz * scl;
}

// ---- fused multi-op MFMA GEMM + BN + ReLU + weighted accumulate ----
// 128x128 tile, 4 waves (2x2), mfma_f32_16x16x32_f16, XOR-swizzled LDS.
__global__ __launch_bounds__(256) void k_mix_mfma(
    MixListH ml, const _Float16* __restrict__ Whall, const float* __restrict__ scale,
    const float* __restrict__ shift, const float* __restrict__ wts,
    float* __restrict__ outf, _Float16* __restrict__ outh, int n) {
  __shared__ _Float16 Xs[128 * 128];
  __shared__ _Float16 Ws[128 * 128];
  const int t = threadIdx.x;
  const int lane = t & 63, w = t >> 6;
  const int wr = w >> 1, wc = w & 1;
  const int l15 = lane & 15, l4 = lane >> 4;
  const int row0 = blockIdx.x * 128;
  const int R = wr * 64, Cb = wc * 64;

  f32x4 oacc[4][4];
#pragma unroll
  for (int m = 0; m < 4; ++m)
#pragma unroll
    for (int nn = 0; nn < 4; ++nn) oacc[m][nn] = (f32x4){0.f, 0.f, 0.f, 0.f};

  const _Float16* Xprev = nullptr;
  for (int o = 0; o < ml.nops; ++o) {
    const _Float16* X = ml.X[o];
    const int op = ml.op[o];
    const _Float16* Wp = Whall + (size_t)op * 16384;
    __syncthreads();  // previous op's MFMA reads done before LDS overwrite
    if (X != Xprev) {
      int r = t >> 1, cb = (t & 1) * 8;
      int grow = row0 + r;
      if (grow < n) {
        const half8* src = (const half8*)(X + (size_t)grow * 128);
#pragma unroll
        for (int i = 0; i < 8; ++i) {
          int c = cb + i;
          *(half8*)&Xs[(r << 7) + ((c ^ (r & 15)) << 3)] = src[c];
        }
      } else {
        half8 z = {0, 0, 0, 0, 0, 0, 0, 0};
#pragma unroll
        for (int i = 0; i < 8; ++i) {
          int c = cb + i;
          *(half8*)&Xs[(r << 7) + ((c ^ (r & 15)) << 3)] = z;
        }
      }
      Xprev = X;
    }
    {
      int r = t >> 1, cb = (t & 1) * 8;
      const half8* src = (const half8*)(Wp + (size_t)r * 128);
#pragma unroll
      for (int i = 0; i < 8; ++i) {
        int c = cb + i;
        *(half8*)&Ws[(r << 7) + ((c ^ (r & 15)) << 3)] = src[c];
      }
    }
    __syncthreads();

    f32x4 acc[4][4];
#pragma unroll
    for (int m = 0; m < 4; ++m)
#pragma unroll
      for (int nn = 0; nn < 4; ++nn) acc[m][nn] = (f32x4){0.f, 0.f, 0.f, 0.f};

#pragma unroll
    for (int ks = 0; ks < 4; ++ks) {
      const int chunk = ks * 4 + l4;
      half8 a[4], b[4];
#pragma unroll
      for (int m = 0; m < 4; ++m) {
        int rr = R + m * 16 + l15;
        a[m] = *(const half8*)&Xs[(rr << 7) + ((chunk ^ (rr & 15)) << 3)];
      }
#pragma unroll
      for (int nn = 0; nn < 4; ++nn) {
        int cc = Cb + nn * 16 + l15;
        b[nn] = *(const half8*)&Ws[(cc << 7) + ((chunk ^ (cc & 15)) << 3)];
      }
#pragma unroll
      for (int m = 0; m < 4; ++m)
#pragma unroll
        for (int nn = 0; nn < 4; ++nn)
          acc[m][nn] = __builtin_amdgcn_mfma_f32_16x16x32_f16(a[m], b[nn], acc[m][nn], 0, 0, 0);
    }

    const float wgt = wts[op];
#pragma unroll
    for (int nn = 0; nn < 4; ++nn) {
      int col = Cb + nn * 16 + l15;
      float sc = scale[op * 128 + col];
      float sh = shift[op * 128 + col];
#pragma unroll
      for (int m = 0; m < 4; ++m)
#pragma unroll
        for (int j = 0; j < 4; ++j) {
          float y = fmaxf(fmaf(acc[m][nn][j], sc, sh), 0.f);
          oacc[m][nn][j] = fmaf(wgt, y, oacc[m][nn][j]);
        }
    }
  }

#pragma unroll
  for (int m = 0; m < 4; ++m)
#pragma unroll
    for (int j = 0; j < 4; ++j) {
      int row = row0 + R + m * 16 + l4 * 4 + j;
      if (row < n) {
#pragma unroll
        for (int nn = 0; nn < 4; ++nn) {
          int col = Cb + nn * 16 + l15;
          float v = oacc[m][nn][j];
          outf[(size_t)row * 128 + col] = v;
          if (outh) outh[(size_t)row * 128 + col] = (_Float16)v;
        }
      }
    }
}

extern "C" void kernel_launch(void* const* d_in, const int* in_sizes, int n_in,
                              void* d_out, int out_size, void* d_ws, size_t ws_size,
                              hipStream_t stream) {
  (void)n_in; (void)out_size; (void)ws_size;
  const int*   edge  = (const int*)d_in[0];
  const float* h     = (const float*)d_in[1];
  const float* h_in  = (const float*)d_in[2];
  const float* wts   = (const float*)d_in[3];
  const float* W     = (const float*)d_in[4];
  // d_in[5] = b : cancels exactly in training-mode BN
  const float* gamma = (const float*)d_in[6];
  const float* beta  = (const float*)d_in[7];
  float* out = (float*)d_out;

  const int E = in_sizes[0] / 2;
  const int N = in_sizes[1] / 128;
  const int* src = edge;
  const int* dst = edge + E;
  const size_t NF = (size_t)N * 128;

  char* ws = (char*)d_ws;
  size_t off = 0;
  auto carve = [&](size_t bytes) -> void* {
    void* p = ws + off;
    off += (bytes + 511) & ~((size_t)511);
    return p;
  };
  int*      degw  = (int*)carve((size_t)N * 4);
  int*      offw  = (int*)carve((size_t)(N + 1) * 4);
  int*      curw  = (int*)carve((size_t)N * 4);
  int*      csrw  = (int*)carve((size_t)E * 4);
  float*    invw  = (float*)carve((size_t)N * 4);
  float*    Ssum  = (float*)carve((size_t)7 * 16384 * 4);
  float*    musum = (float*)carve((size_t)7 * 128 * 4);
  float*    U     = (float*)carve((size_t)18 * 16384 * 4);
  float*    scl   = (float*)carve((size_t)18 * 128 * 4);
  float*    shf   = (float*)carve((size_t)18 * 128 * 4);
  _Float16* Wh    = (_Float16*)carve((size_t)18 * 16384 * 2);
  _Float16* hb    = (_Float16*)carve(NF * 2);
  _Float16* h_inb = (_Float16*)carve(NF * 2);
  _Float16* agg0b = (_Float16*)carve(NF * 2);
  _Float16* agg1b = (_Float16*)carve(NF * 2);
  _Float16* agg2b = (_Float16*)carve(NF * 2);
  _Float16* s1b   = (_Float16*)carve(NF * 2);
  _Float16* s2b   = (_Float16*)carve(NF * 2);

  float* s1 = out;
  float* s2 = out + NF;
  float* s3 = out + 2 * NF;

  hipMemsetAsync(degw, 0, (size_t)N * 4, stream);
  hipMemsetAsync(Ssum, 0, (size_t)7 * 16384 * 4, stream);
  hipMemsetAsync(musum, 0, (size_t)7 * 128 * 4, stream);

  const int gE    = (E + 255) / 256;
  const int gAgg  = (N + 3) / 4;
  const int gMix  = (N + 127) / 128;
  const int gStat = (N + 255) / 256;

  // fp16 copies
  k_f2h<<<2048, 256, 0, stream>>>(h, hb, (int)(NF / 4));
  k_f2h<<<2048, 256, 0, stream>>>(h_in, h_inb, (int)(NF / 4));
  k_f2h<<<288, 256, 0, stream>>>(W, Wh, 18 * 16384 / 4);

  // CSR build
  k_hist<<<gE, 256, 0, stream>>>(dst, degw, E);
  k_scan<<<1, 1024, 0, stream>>>(degw, offw, curw, invw, N);
  k_scatter<<<gE, 256, 0, stream>>>(src, dst, curw, csrw, E);
  k_agg<<<gAgg, 256, 0, stream>>>(hb, csrw, offw, invw, agg0b, N);

  auto stats = [&](const _Float16* X, int slot) {
    k_stats_part<<<gStat, 256, 0, stream>>>(X, Ssum + (size_t)slot * 16384,
                                            musum + (size_t)slot * 128, N);
  };

  // ---- stage 1 ----
  stats(agg0b, 0); stats(hb, 1); stats(h_inb, 2);
  OpList pa{}; { int v[9] = {0,1,2,3,4,5,9,10,11}; for (int i = 0; i < 9; ++i) pa.ops[i] = v[i]; }
  k_varU<<<dim3(2, 9), 256, 0, stream>>>(W, Ssum, U, pa);
  k_bnfinal<<<9, 128, 0, stream>>>(pa, W, U, musum, gamma, beta, scl, shf, N);
  MixListH m1{}; m1.nops = 3;
  m1.X[0] = agg0b; m1.op[0] = 0; m1.X[1] = hb; m1.op[1] = 1; m1.X[2] = h_inb; m1.op[2] = 2;
  k_mix_mfma<<<gMix, 256, 0, stream>>>(m1, Wh, scl, shf, wts, s1, s1b, N);

  // ---- stage 2 ----
  k_agg<<<gAgg, 256, 0, stream>>>(s1b, csrw, offw, invw, agg1b, N);
  stats(s1b, 3); stats(agg1b, 4);
  OpList pb{}; { int v[6] = {6,7,8,12,13,14}; for (int i = 0; i < 6; ++i) pb.ops[i] = v[i]; }
  k_varU<<<dim3(2, 6), 256, 0, stream>>>(W, Ssum, U, pb);
  k_bnfinal<<<6, 128, 0, stream>>>(pb, W, U, musum, gamma, beta, scl, shf, N);
  MixListH m2{}; m2.nops = 6;  // same-X ops adjacent to skip X restaging
  m2.X[0] = agg0b; m2.op[0] = 3;
  m2.X[1] = hb;    m2.op[1] = 4;
  m2.X[2] = h_inb; m2.op[2] = 5;
  m2.X[3] = h_inb; m2.op[3] = 8;
  m2.X[4] = agg1b; m2.op[4] = 6;
  m2.X[5] = s1b;   m2.op[5] = 7;
  k_mix_mfma<<<gMix, 256, 0, stream>>>(m2, Wh, scl, shf, wts, s2, s2b, N);

  // ---- stage 3 ----
  k_agg<<<gAgg, 256, 0, stream>>>(s2b, csrw, offw, invw, agg2b, N);
  stats(s2b, 5); stats(agg2b, 6);
  OpList pc{}; { int v[3] = {15,16,17}; for (int i = 0; i < 3; ++i) pc.ops[i] = v[i]; }
  k_varU<<<dim3(2, 3), 256, 0, stream>>>(W, Ssum, U, pc);
  k_bnfinal<<<3, 128, 0, stream>>>(pc, W, U, musum, gamma, beta, scl, shf, N);
  MixListH m3{}; m3.nops = 9;
  m3.X[0] = agg0b; m3.op[0] = 9;
  m3.X[1] = hb;    m3.op[1] = 10;
  m3.X[2] = h_inb; m3.op[2] = 11;
  m3.X[3] = h_inb; m3.op[3] = 14;
  m3.X[4] = h_inb; m3.op[4] = 17;
  m3.X[5] = agg1b; m3.op[5] = 12;
  m3.X[6] = s1b;   m3.op[6] = 13;
  m3.X[7] = agg2b; m3.op[7] = 15;
  m3.X[8] = s2b;   m3.op[8] = 16;
  k_mix_mfma<<<gMix, 256, 0, stream>>>(m3, Wh, scl, shf, wts, s3, nullptr, N);
}

// Round 6
// 1006.287 us; speedup vs baseline: 2.6924x; 1.7915x over previous
//
#include <hip/hip_runtime.h>
#include <hip/hip_fp16.h>

// branches: 0=agg(h) 1=h 2=h_in 3=s1 4=agg(s1) 5=s2 6=agg(s2)
static __device__ const int BRTAB[18] = {0,1,2, 0,1,2, 4,3,2, 0,1,2, 4,3,2, 6,5,2};

struct OpList   { int ops[9]; };
struct MixListH { const _Float16* X[9]; int op[9]; int nops; };

using half8 = __attribute__((ext_vector_type(8))) _Float16;
using half4 = __attribute__((ext_vector_type(4))) _Float16;
using f32x4 = __attribute__((ext_vector_type(4))) float;

__device__ __forceinline__ float4 f4fma(float a, float4 b, float4 c) {
  c.x = fmaf(a, b.x, c.x); c.y = fmaf(a, b.y, c.y);
  c.z = fmaf(a, b.z, c.z); c.w = fmaf(a, b.w, c.w);
  return c;
}

// ---- fp32 -> fp16 conversion ----
__global__ void k_f2h(const float* __restrict__ x, _Float16* __restrict__ y, int n4) {
  for (int i = blockIdx.x * 256 + threadIdx.x; i < n4; i += gridDim.x * 256) {
    float4 v = ((const float4*)x)[i];
    half4 o = { (_Float16)v.x, (_Float16)v.y, (_Float16)v.z, (_Float16)v.w };
    ((half4*)y)[i] = o;
  }
}

// ---- degree histogram ----
__global__ void k_hist(const int* __restrict__ dst, int* __restrict__ deg, int E) {
  int e = blockIdx.x * 256 + threadIdx.x;
  if (e < E) atomicAdd(&deg[dst[e]], 1);
}

// ---- exclusive prefix-sum over degrees (single block) ----
__global__ __launch_bounds__(1024) void k_scan(
    const int* __restrict__ deg, int* __restrict__ off, int* __restrict__ cur,
    float* __restrict__ inv_deg, int n) {
  __shared__ int wsum[16];
  const int t = threadIdx.x, lane = t & 63, wid = t >> 6;
  int running = 0;
  for (int base = 0; base < n; base += 1024) {
    __syncthreads();
    int i = base + t;
    int v = (i < n) ? deg[i] : 0;
    int x = v;
#pragma unroll
    for (int s = 1; s < 64; s <<= 1) {
      int u = __shfl_up(x, (unsigned)s, 64);
      if (lane >= s) x += u;
    }
    if (lane == 63) wsum[wid] = x;
    __syncthreads();
    if (t < 16) {
      int w = wsum[t];
#pragma unroll
      for (int s = 1; s < 16; s <<= 1) {
        int u = __shfl_up(w, (unsigned)s, 16);
        if (t >= s) w += u;
      }
      wsum[t] = w;
    }
    __syncthreads();
    int excl = running + x + ((wid > 0) ? wsum[wid - 1] : 0) - v;
    if (i < n) {
      off[i] = excl; cur[i] = excl;
      inv_deg[i] = 1.0f / fmaxf((float)v, 1.0f);
    }
    running += wsum[15];
  }
  if (t == 0) off[n] = running;
}

// ---- bucket edges by dst ----
__global__ void k_scatter(const int* __restrict__ src, const int* __restrict__ dst,
                          int* __restrict__ cur, int* __restrict__ csr, int E) {
  int e = blockIdx.x * 256 + threadIdx.x;
  if (e < E) {
    int pos = atomicAdd(&cur[dst[e]], 1);
    csr[pos] = src[e];
  }
}

// ---- mean aggregation: one wave per node, fp16 gather, f32 accum, fp16 out ----
__global__ void k_agg(const _Float16* __restrict__ x, const int* __restrict__ csr,
                      const int* __restrict__ off, const float* __restrict__ inv_deg,
                      _Float16* __restrict__ outb, int n) {
  int node = blockIdx.x * 4 + (threadIdx.x >> 6);
  int lane = threadIdx.x & 63;
  if (node >= n) return;
  int e0 = off[node], e1 = off[node + 1];
  const __half2* xp = (const __half2*)x;
  float ax = 0.f, ay = 0.f;
  for (int e = e0; e < e1; ++e) {
    int s = csr[e];
    float2 v = __half22float2(xp[(size_t)s * 64 + lane]);
    ax += v.x; ay += v.y;
  }
  float iv = inv_deg[node];
  ((__half2*)outb)[(size_t)node * 64 + lane] = __floats2half2_rn(ax * iv, ay * iv);
}

// ---- MFMA second moments: S += X_chunk^T @ X_chunk, mus += colsum ----
// 128 rows/block, LDS holds transposed+swizzled Xt[c][k], 4 waves each own a
// 64x64 quadrant of the 128x128 output, atomicAdd into S.
__global__ __launch_bounds__(256) void k_stats_mfma(
    const _Float16* __restrict__ X, float* __restrict__ S,
    float* __restrict__ mus, int n) {
  __shared__ _Float16 Xt[128 * 128];  // 32 KB, Xt[c][k] with chunk-XOR swizzle
  const int t = threadIdx.x;
  const int lane = t & 63, w = t >> 6;
  const int wr = w >> 1, wc = w & 1;
  const int l15 = lane & 15, l4 = lane >> 4;
  const int base = blockIdx.x * 128;

  // stage: coalesced row loads, scatter-transpose into swizzled LDS
#pragma unroll
  for (int jj = 0; jj < 8; ++jj) {
    int flat = t + jj * 256;          // 0..2047
    int r = flat >> 4;                // source row 0..127
    int c8 = flat & 15;               // col-octet
    int row = base + r;
    half8 v = {0, 0, 0, 0, 0, 0, 0, 0};
    if (row < n) v = *(const half8*)(X + (size_t)row * 128 + c8 * 8);
#pragma unroll
    for (int i = 0; i < 8; ++i) {
      int c = c8 * 8 + i;
      int swz = (c & 15) ^ ((c >> 4) & 15);
      Xt[c * 128 + (((r >> 3) ^ swz) << 3) + (r & 7)] = v[i];
    }
  }
  __syncthreads();

  f32x4 acc[4][4];
#pragma unroll
  for (int m = 0; m < 4; ++m)
#pragma unroll
    for (int nn = 0; nn < 4; ++nn) acc[m][nn] = (f32x4){0.f, 0.f, 0.f, 0.f};

#pragma unroll
  for (int ks = 0; ks < 4; ++ks) {
    const int k8 = ks * 4 + l4;
    half8 a[4], b[4];
#pragma unroll
    for (int m = 0; m < 4; ++m) {
      int c = wr * 64 + m * 16 + l15;
      int swz = (c & 15) ^ ((c >> 4) & 15);
      a[m] = *(const half8*)&Xt[c * 128 + ((k8 ^ swz) << 3)];
    }
#pragma unroll
    for (int nn = 0; nn < 4; ++nn) {
      int c = wc * 64 + nn * 16 + l15;
      int swz = (c & 15) ^ ((c >> 4) & 15);
      b[nn] = *(const half8*)&Xt[c * 128 + ((k8 ^ swz) << 3)];
    }
#pragma unroll
    for (int m = 0; m < 4; ++m)
#pragma unroll
      for (int nn = 0; nn < 4; ++nn)
        acc[m][nn] = __builtin_amdgcn_mfma_f32_16x16x32_f16(a[m], b[nn], acc[m][nn], 0, 0, 0);
  }

#pragma unroll
  for (int m = 0; m < 4; ++m)
#pragma unroll
    for (int nn = 0; nn < 4; ++nn)
#pragma unroll
      for (int j = 0; j < 4; ++j) {
        int rr = wr * 64 + m * 16 + l4 * 4 + j;
        int cc = wc * 64 + nn * 16 + l15;
        atomicAdd(&S[rr * 128 + cc], acc[m][nn][j]);
      }

  // column sums from staged (zero-padded) data
  if (t < 128) {
    int c = t;
    int swz = (c & 15) ^ ((c >> 4) & 15);
    float s = 0.f;
#pragma unroll
    for (int k8 = 0; k8 < 16; ++k8) {
      half8 v = *(const half8*)&Xt[c * 128 + ((k8 ^ swz) << 3)];
#pragma unroll
      for (int j = 0; j < 8; ++j) s += (float)v[j];
    }
    atomicAdd(&mus[c], s);
  }
}

// ---- U[op] = W[op] @ S[br(op)] ----
__global__ __launch_bounds__(256) void k_varU(
    const float* __restrict__ Wall, const float* __restrict__ Sall,
    float* __restrict__ U, OpList ol) {
  const int op = ol.ops[blockIdx.y];
  const int br = BRTAB[op];
  const float* A = Wall + (size_t)op * 16384;
  const float* B = Sall + (size_t)br * 16384;
  const int d0 = blockIdx.x * 64;
  __shared__ float As[64][32];
  __shared__ float Bs[32][128];
  const int t = threadIdx.x, tr = t >> 5, tc = t & 31;
  float4 acc[8];
#pragma unroll
  for (int i = 0; i < 8; ++i) acc[i] = make_float4(0.f, 0.f, 0.f, 0.f);
  for (int kc = 0; kc < 4; ++kc) {
    const int k0 = kc * 32;
    __syncthreads();
#pragma unroll
    for (int i = 0; i < 2; ++i) {
      int f = t + i * 256;
      int r = f >> 3, kq = f & 7;
      *(float4*)&As[r][kq * 4] = *(const float4*)&A[(d0 + r) * 128 + k0 + kq * 4];
    }
#pragma unroll
    for (int i = 0; i < 4; ++i) {
      int f = t + i * 256;
      int k = f >> 5, c4 = f & 31;
      *(float4*)&Bs[k][c4 * 4] = *(const float4*)&B[(k0 + k) * 128 + c4 * 4];
    }
    __syncthreads();
#pragma unroll
    for (int kq = 0; kq < 8; ++kq) {
      float4 b0 = *(float4*)&Bs[kq * 4 + 0][tc * 4];
      float4 b1 = *(float4*)&Bs[kq * 4 + 1][tc * 4];
      float4 b2 = *(float4*)&Bs[kq * 4 + 2][tc * 4];
      float4 b3 = *(float4*)&Bs[kq * 4 + 3][tc * 4];
#pragma unroll
      for (int i = 0; i < 8; ++i) {
        float4 av = *(float4*)&As[tr * 8 + i][kq * 4];
        acc[i] = f4fma(av.x, b0, acc[i]);
        acc[i] = f4fma(av.y, b1, acc[i]);
        acc[i] = f4fma(av.z, b2, acc[i]);
        acc[i] = f4fma(av.w, b3, acc[i]);
      }
    }
  }
#pragma unroll
  for (int i = 0; i < 8; ++i)
    *(float4*)&U[(size_t)op * 16384 + (d0 + tr * 8 + i) * 128 + tc * 4] = acc[i];
}

// ---- BN fold: scale = g*rsqrt(var+eps), shift = beta - mean_z*scale ----
__global__ void k_bnfinal(OpList ol, const float* __restrict__ Wall,
                          const float* __restrict__ U, const float* __restrict__ mus,
                          const float* __restrict__ gamma, const float* __restrict__ beta,
                          float* __restrict__ scale, float* __restrict__ shift, int n) {
  const int op = ol.ops[blockIdx.x];
  const int br = BRTAB[op];
  const int d = threadIdx.x;
  __shared__ __align__(16) float muL[128];
  const float invN = 1.0f / (float)n;
  muL[d] = mus[br * 128 + d] * invN;
  __syncthreads();
  const float4* Wr = (const float4*)(Wall + (size_t)op * 16384 + d * 128);
  const float4* Ur = (const float4*)(U + (size_t)op * 16384 + d * 128);
  const float4* m4 = (const float4*)muL;
  float q = 0.f, mz = 0.f;
#pragma unroll 8
  for (int j = 0; j < 32; ++j) {
    float4 w = Wr[j], u = Ur[j], m = m4[j];
    q  += w.x * u.x + w.y * u.y + w.z * u.z + w.w * u.w;
    mz += w.x * m.x + w.y * m.y + w.z * m.z + w.w * m.w;
  }
  float var = fmaxf(q * invN - mz * mz, 0.0f);
  float is = 1.0f / sqrtf(var + 1e-5f);
  float scl = gamma[op * 128 + d] * is;
  scale[op * 128 + d] = scl;
  shift[op * 128 + d] = beta[op * 128 + d] - mz * scl;
}

// ---- fused multi-op MFMA GEMM + BN + ReLU + weighted accumulate ----
__global__ __launch_bounds__(256) void k_mix_mfma(
    MixListH ml, const _Float16* __restrict__ Whall, const float* __restrict__ scale,
    const float* __restrict__ shift, const float* __restrict__ wts,
    float* __restrict__ outf, _Float16* __restrict__ outh, int n) {
  __shared__ _Float16 Xs[128 * 128];
  __shared__ _Float16 Ws[128 * 128];
  const int t = threadIdx.x;
  const int lane = t & 63, w = t >> 6;
  const int wr = w >> 1, wc = w & 1;
  const int l15 = lane & 15, l4 = lane >> 4;
  const int row0 = blockIdx.x * 128;
  const int R = wr * 64, Cb = wc * 64;

  f32x4 oacc[4][4];
#pragma unroll
  for (int m = 0; m < 4; ++m)
#pragma unroll
    for (int nn = 0; nn < 4; ++nn) oacc[m][nn] = (f32x4){0.f, 0.f, 0.f, 0.f};

  const _Float16* Xprev = nullptr;
  for (int o = 0; o < ml.nops; ++o) {
    const _Float16* X = ml.X[o];
    const int op = ml.op[o];
    const _Float16* Wp = Whall + (size_t)op * 16384;
    __syncthreads();
    if (X != Xprev) {
      int r = t >> 1, cb = (t & 1) * 8;
      int grow = row0 + r;
      if (grow < n) {
        const half8* src = (const half8*)(X + (size_t)grow * 128);
#pragma unroll
        for (int i = 0; i < 8; ++i) {
          int c = cb + i;
          *(half8*)&Xs[(r << 7) + ((c ^ (r & 15)) << 3)] = src[c];
        }
      } else {
        half8 z = {0, 0, 0, 0, 0, 0, 0, 0};
#pragma unroll
        for (int i = 0; i < 8; ++i) {
          int c = cb + i;
          *(half8*)&Xs[(r << 7) + ((c ^ (r & 15)) << 3)] = z;
        }
      }
      Xprev = X;
    }
    {
      int r = t >> 1, cb = (t & 1) * 8;
      const half8* src = (const half8*)(Wp + (size_t)r * 128);
#pragma unroll
      for (int i = 0; i < 8; ++i) {
        int c = cb + i;
        *(half8*)&Ws[(r << 7) + ((c ^ (r & 15)) << 3)] = src[c];
      }
    }
    __syncthreads();

    f32x4 acc[4][4];
#pragma unroll
    for (int m = 0; m < 4; ++m)
#pragma unroll
      for (int nn = 0; nn < 4; ++nn) acc[m][nn] = (f32x4){0.f, 0.f, 0.f, 0.f};

#pragma unroll
    for (int ks = 0; ks < 4; ++ks) {
      const int chunk = ks * 4 + l4;
      half8 a[4], b[4];
#pragma unroll
      for (int m = 0; m < 4; ++m) {
        int rr = R + m * 16 + l15;
        a[m] = *(const half8*)&Xs[(rr << 7) + ((chunk ^ (rr & 15)) << 3)];
      }
#pragma unroll
      for (int nn = 0; nn < 4; ++nn) {
        int cc = Cb + nn * 16 + l15;
        b[nn] = *(const half8*)&Ws[(cc << 7) + ((chunk ^ (cc & 15)) << 3)];
      }
#pragma unroll
      for (int m = 0; m < 4; ++m)
#pragma unroll
        for (int nn = 0; nn < 4; ++nn)
          acc[m][nn] = __builtin_amdgcn_mfma_f32_16x16x32_f16(a[m], b[nn], acc[m][nn], 0, 0, 0);
    }

    const float wgt = wts[op];
#pragma unroll
    for (int nn = 0; nn < 4; ++nn) {
      int col = Cb + nn * 16 + l15;
      float sc = scale[op * 128 + col];
      float sh = shift[op * 128 + col];
#pragma unroll
      for (int m = 0; m < 4; ++m)
#pragma unroll
        for (int j = 0; j < 4; ++j) {
          float y = fmaxf(fmaf(acc[m][nn][j], sc, sh), 0.f);
          oacc[m][nn][j] = fmaf(wgt, y, oacc[m][nn][j]);
        }
    }
  }

#pragma unroll
  for (int m = 0; m < 4; ++m)
#pragma unroll
    for (int j = 0; j < 4; ++j) {
      int row = row0 + R + m * 16 + l4 * 4 + j;
      if (row < n) {
#pragma unroll
        for (int nn = 0; nn < 4; ++nn) {
          int col = Cb + nn * 16 + l15;
          float v = oacc[m][nn][j];
          outf[(size_t)row * 128 + col] = v;
          if (outh) outh[(size_t)row * 128 + col] = (_Float16)v;
        }
      }
    }
}

extern "C" void kernel_launch(void* const* d_in, const int* in_sizes, int n_in,
                              void* d_out, int out_size, void* d_ws, size_t ws_size,
                              hipStream_t stream) {
  (void)n_in; (void)out_size; (void)ws_size;
  const int*   edge  = (const int*)d_in[0];
  const float* h     = (const float*)d_in[1];
  const float* h_in  = (const float*)d_in[2];
  const float* wts   = (const float*)d_in[3];
  const float* W     = (const float*)d_in[4];
  const float* gamma = (const float*)d_in[6];
  const float* beta  = (const float*)d_in[7];
  float* out = (float*)d_out;

  const int E = in_sizes[0] / 2;
  const int N = in_sizes[1] / 128;
  const int* src = edge;
  const int* dst = edge + E;
  const size_t NF = (size_t)N * 128;

  char* ws = (char*)d_ws;
  size_t off = 0;
  auto carve = [&](size_t bytes) -> void* {
    void* p = ws + off;
    off += (bytes + 511) & ~((size_t)511);
    return p;
  };
  int*      degw  = (int*)carve((size_t)N * 4);
  int*      offw  = (int*)carve((size_t)(N + 1) * 4);
  int*      curw  = (int*)carve((size_t)N * 4);
  int*      csrw  = (int*)carve((size_t)E * 4);
  float*    invw  = (float*)carve((size_t)N * 4);
  float*    Ssum  = (float*)carve((size_t)7 * 16384 * 4);
  float*    musum = (float*)carve((size_t)7 * 128 * 4);
  float*    U     = (float*)carve((size_t)18 * 16384 * 4);
  float*    scl   = (float*)carve((size_t)18 * 128 * 4);
  float*    shf   = (float*)carve((size_t)18 * 128 * 4);
  _Float16* Wh    = (_Float16*)carve((size_t)18 * 16384 * 2);
  _Float16* hb    = (_Float16*)carve(NF * 2);
  _Float16* h_inb = (_Float16*)carve(NF * 2);
  _Float16* agg0b = (_Float16*)carve(NF * 2);
  _Float16* agg1b = (_Float16*)carve(NF * 2);
  _Float16* agg2b = (_Float16*)carve(NF * 2);
  _Float16* s1b   = (_Float16*)carve(NF * 2);
  _Float16* s2b   = (_Float16*)carve(NF * 2);

  float* s1 = out;
  float* s2 = out + NF;
  float* s3 = out + 2 * NF;

  hipMemsetAsync(degw, 0, (size_t)N * 4, stream);
  hipMemsetAsync(Ssum, 0, (size_t)7 * 16384 * 4, stream);
  hipMemsetAsync(musum, 0, (size_t)7 * 128 * 4, stream);

  const int gE    = (E + 255) / 256;
  const int gAgg  = (N + 3) / 4;
  const int gMix  = (N + 127) / 128;
  const int gStat = (N + 127) / 128;

  k_f2h<<<2048, 256, 0, stream>>>(h, hb, (int)(NF / 4));
  k_f2h<<<2048, 256, 0, stream>>>(h_in, h_inb, (int)(NF / 4));
  k_f2h<<<288, 256, 0, stream>>>(W, Wh, 18 * 16384 / 4);

  k_hist<<<gE, 256, 0, stream>>>(dst, degw, E);
  k_scan<<<1, 1024, 0, stream>>>(degw, offw, curw, invw, N);
  k_scatter<<<gE, 256, 0, stream>>>(src, dst, curw, csrw, E);
  k_agg<<<gAgg, 256, 0, stream>>>(hb, csrw, offw, invw, agg0b, N);

  auto stats = [&](const _Float16* X, int slot) {
    k_stats_mfma<<<gStat, 256, 0, stream>>>(X, Ssum + (size_t)slot * 16384,
                                            musum + (size_t)slot * 128, N);
  };

  // ---- stage 1 ----
  stats(agg0b, 0); stats(hb, 1); stats(h_inb, 2);
  OpList pa{}; { int v[9] = {0,1,2,3,4,5,9,10,11}; for (int i = 0; i < 9; ++i) pa.ops[i] = v[i]; }
  k_varU<<<dim3(2, 9), 256, 0, stream>>>(W, Ssum, U, pa);
  k_bnfinal<<<9, 128, 0, stream>>>(pa, W, U, musum, gamma, beta, scl, shf, N);
  MixListH m1{}; m1.nops = 3;
  m1.X[0] = agg0b; m1.op[0] = 0; m1.X[1] = hb; m1.op[1] = 1; m1.X[2] = h_inb; m1.op[2] = 2;
  k_mix_mfma<<<gMix, 256, 0, stream>>>(m1, Wh, scl, shf, wts, s1, s1b, N);

  // ---- stage 2 ----
  k_agg<<<gAgg, 256, 0, stream>>>(s1b, csrw, offw, invw, agg1b, N);
  stats(s1b, 3); stats(agg1b, 4);
  OpList pb{}; { int v[6] = {6,7,8,12,13,14}; for (int i = 0; i < 6; ++i) pb.ops[i] = v[i]; }
  k_varU<<<dim3(2, 6), 256, 0, stream>>>(W, Ssum, U, pb);
  k_bnfinal<<<6, 128, 0, stream>>>(pb, W, U, musum, gamma, beta, scl, shf, N);
  MixListH m2{}; m2.nops = 6;
  m2.X[0] = agg0b; m2.op[0] = 3;
  m2.X[1] = hb;    m2.op[1] = 4;
  m2.X[2] = h_inb; m2.op[2] = 5;
  m2.X[3] = h_inb; m2.op[3] = 8;
  m2.X[4] = agg1b; m2.op[4] = 6;
  m2.X[5] = s1b;   m2.op[5] = 7;
  k_mix_mfma<<<gMix, 256, 0, stream>>>(m2, Wh, scl, shf, wts, s2, s2b, N);

  // ---- stage 3 ----
  k_agg<<<gAgg, 256, 0, stream>>>(s2b, csrw, offw, invw, agg2b, N);
  stats(s2b, 5); stats(agg2b, 6);
  OpList pc{}; { int v[3] = {15,16,17}; for (int i = 0; i < 3; ++i) pc.ops[i] = v[i]; }
  k_varU<<<dim3(2, 3), 256, 0, stream>>>(W, Ssum, U, pc);
  k_bnfinal<<<3, 128, 0, stream>>>(pc, W, U, musum, gamma, beta, scl, shf, N);
  MixListH m3{}; m3.nops = 9;
  m3.X[0] = agg0b; m3.op[0] = 9;
  m3.X[1] = hb;    m3.op[1] = 10;
  m3.X[2] = h_inb; m3.op[2] = 11;
  m3.X[3] = h_inb; m3.op[3] = 14;
  m3.X[4] = h_inb; m3.op[4] = 17;
  m3.X[5] = agg1b; m3.op[5] = 12;
  m3.X[6] = s1b;   m3.op[6] = 13;
  m3.X[7] = agg2b; m3.op[7] = 15;
  m3.X[8] = s2b;   m3.op[8] = 16;
  k_mix_mfma<<<gMix, 256, 0, stream>>>(m3, Wh, scl, shf, wts, s3, nullptr, N);
}

// Round 7
// 784.671 us; speedup vs baseline: 3.4528x; 1.2824x over previous
//
#include <hip/hip_runtime.h>
#include <hip/hip_fp16.h>

// branches: 0=agg(h) 1=h 2=h_in 3=s1 4=agg(s1) 5=s2 6=agg(s2)
static __device__ const int BRTAB[18] = {0,1,2, 0,1,2, 4,3,2, 0,1,2, 4,3,2, 6,5,2};

struct OpList   { int ops[9]; };
struct MixListH { const _Float16* X[9]; int op[9]; int nops; };
struct StatsList { const _Float16* X[3]; float* S[3]; float* mus[3]; };

using half8 = __attribute__((ext_vector_type(8))) _Float16;
using half4 = __attribute__((ext_vector_type(4))) _Float16;
using f32x4 = __attribute__((ext_vector_type(4))) float;

__device__ __forceinline__ float4 f4fma(float a, float4 b, float4 c) {
  c.x = fmaf(a, b.x, c.x); c.y = fmaf(a, b.y, c.y);
  c.z = fmaf(a, b.z, c.z); c.w = fmaf(a, b.w, c.w);
  return c;
}

// ---- fp32 -> fp16 conversion ----
__global__ void k_f2h(const float* __restrict__ x, _Float16* __restrict__ y, int n4) {
  for (int i = blockIdx.x * 256 + threadIdx.x; i < n4; i += gridDim.x * 256) {
    float4 v = ((const float4*)x)[i];
    half4 o = { (_Float16)v.x, (_Float16)v.y, (_Float16)v.z, (_Float16)v.w };
    ((half4*)y)[i] = o;
  }
}

// ---- degree histogram ----
__global__ void k_hist(const int* __restrict__ dst, int* __restrict__ deg, int E) {
  int e = blockIdx.x * 256 + threadIdx.x;
  if (e < E) atomicAdd(&deg[dst[e]], 1);
}

// ---- exclusive prefix-sum over degrees (single block) ----
__global__ __launch_bounds__(1024) void k_scan(
    const int* __restrict__ deg, int* __restrict__ off, int* __restrict__ cur,
    float* __restrict__ inv_deg, int n) {
  __shared__ int wsum[16];
  const int t = threadIdx.x, lane = t & 63, wid = t >> 6;
  int running = 0;
  for (int base = 0; base < n; base += 1024) {
    __syncthreads();
    int i = base + t;
    int v = (i < n) ? deg[i] : 0;
    int x = v;
#pragma unroll
    for (int s = 1; s < 64; s <<= 1) {
      int u = __shfl_up(x, (unsigned)s, 64);
      if (lane >= s) x += u;
    }
    if (lane == 63) wsum[wid] = x;
    __syncthreads();
    if (t < 16) {
      int w = wsum[t];
#pragma unroll
      for (int s = 1; s < 16; s <<= 1) {
        int u = __shfl_up(w, (unsigned)s, 16);
        if (t >= s) w += u;
      }
      wsum[t] = w;
    }
    __syncthreads();
    int excl = running + x + ((wid > 0) ? wsum[wid - 1] : 0) - v;
    if (i < n) {
      off[i] = excl; cur[i] = excl;
      inv_deg[i] = 1.0f / fmaxf((float)v, 1.0f);
    }
    running += wsum[15];
  }
  if (t == 0) off[n] = running;
}

// ---- bucket edges by dst ----
__global__ void k_scatter(const int* __restrict__ src, const int* __restrict__ dst,
                          int* __restrict__ cur, int* __restrict__ csr, int E) {
  int e = blockIdx.x * 256 + threadIdx.x;
  if (e < E) {
    int pos = atomicAdd(&cur[dst[e]], 1);
    csr[pos] = src[e];
  }
}

// ---- mean aggregation: wave = 4 edge-groups x 16 lanes, 16B/lane gathers ----
// Each group pulls a whole 256B row per load instr; 4 rows in flight; csr
// index prefetched one iteration ahead (software pipeline).
__global__ void k_agg(const _Float16* __restrict__ x, const int* __restrict__ csr,
                      const int* __restrict__ off, const float* __restrict__ inv_deg,
                      _Float16* __restrict__ outb, int n) {
  int node = blockIdx.x * 4 + (threadIdx.x >> 6);
  int lane = threadIdx.x & 63;
  if (node >= n) return;
  const int g = lane >> 4;       // edge-group 0..3
  const int d8 = lane & 15;      // dim-octet: dims d8*8 .. d8*8+7
  int e0 = off[node], e1 = off[node + 1];

  float acc[8];
#pragma unroll
  for (int j = 0; j < 8; ++j) acc[j] = 0.f;

  int e = e0 + g;
  int s_next = (e < e1) ? csr[e] : 0;
  while (e < e1) {
    int s = s_next;
    int e2 = e + 4;
    if (e2 < e1) s_next = csr[e2];
    half8 v = *(const half8*)(x + (size_t)s * 128 + d8 * 8);
#pragma unroll
    for (int j = 0; j < 8; ++j) acc[j] += (float)v[j];
    e = e2;
  }
  // reduce across the 4 edge-groups (lanes sharing d8)
#pragma unroll
  for (int j = 0; j < 8; ++j) {
    acc[j] += __shfl_xor(acc[j], 16, 64);
    acc[j] += __shfl_xor(acc[j], 32, 64);
  }
  if (g == 0) {
    float iv = inv_deg[node];
    half8 o;
#pragma unroll
    for (int j = 0; j < 8; ++j) o[j] = (_Float16)(acc[j] * iv);
    *(half8*)(outb + (size_t)node * 128 + d8 * 8) = o;
  }
}

// ---- MFMA second moments, batched over up to 3 branches (blockIdx.y) ----
// S += X_chunk^T @ X_chunk, mus += colsum. 128 rows/block, transposed+swizzled
// LDS, 4 waves own 64x64 output quadrants, atomicAdd into S.
__global__ __launch_bounds__(256) void k_stats_mfma(
    StatsList sl, int n) {
  const _Float16* __restrict__ X = sl.X[blockIdx.y];
  float* __restrict__ S   = sl.S[blockIdx.y];
  float* __restrict__ mus = sl.mus[blockIdx.y];
  __shared__ _Float16 Xt[128 * 128];  // 32 KB, Xt[c][k] with chunk-XOR swizzle
  const int t = threadIdx.x;
  const int lane = t & 63, w = t >> 6;
  const int wr = w >> 1, wc = w & 1;
  const int l15 = lane & 15, l4 = lane >> 4;
  const int base = blockIdx.x * 128;

#pragma unroll
  for (int jj = 0; jj < 8; ++jj) {
    int flat = t + jj * 256;
    int r = flat >> 4;
    int c8 = flat & 15;
    int row = base + r;
    half8 v = {0, 0, 0, 0, 0, 0, 0, 0};
    if (row < n) v = *(const half8*)(X + (size_t)row * 128 + c8 * 8);
#pragma unroll
    for (int i = 0; i < 8; ++i) {
      int c = c8 * 8 + i;
      int swz = (c & 15) ^ ((c >> 4) & 15);
      Xt[c * 128 + (((r >> 3) ^ swz) << 3) + (r & 7)] = v[i];
    }
  }
  __syncthreads();

  f32x4 acc[4][4];
#pragma unroll
  for (int m = 0; m < 4; ++m)
#pragma unroll
    for (int nn = 0; nn < 4; ++nn) acc[m][nn] = (f32x4){0.f, 0.f, 0.f, 0.f};

#pragma unroll
  for (int ks = 0; ks < 4; ++ks) {
    const int k8 = ks * 4 + l4;
    half8 a[4], b[4];
#pragma unroll
    for (int m = 0; m < 4; ++m) {
      int c = wr * 64 + m * 16 + l15;
      int swz = (c & 15) ^ ((c >> 4) & 15);
      a[m] = *(const half8*)&Xt[c * 128 + ((k8 ^ swz) << 3)];
    }
#pragma unroll
    for (int nn = 0; nn < 4; ++nn) {
      int c = wc * 64 + nn * 16 + l15;
      int swz = (c & 15) ^ ((c >> 4) & 15);
      b[nn] = *(const half8*)&Xt[c * 128 + ((k8 ^ swz) << 3)];
    }
#pragma unroll
    for (int m = 0; m < 4; ++m)
#pragma unroll
      for (int nn = 0; nn < 4; ++nn)
        acc[m][nn] = __builtin_amdgcn_mfma_f32_16x16x32_f16(a[m], b[nn], acc[m][nn], 0, 0, 0);
  }

#pragma unroll
  for (int m = 0; m < 4; ++m)
#pragma unroll
    for (int nn = 0; nn < 4; ++nn)
#pragma unroll
      for (int j = 0; j < 4; ++j) {
        int rr = wr * 64 + m * 16 + l4 * 4 + j;
        int cc = wc * 64 + nn * 16 + l15;
        atomicAdd(&S[rr * 128 + cc], acc[m][nn][j]);
      }

  if (t < 128) {
    int c = t;
    int swz = (c & 15) ^ ((c >> 4) & 15);
    float s = 0.f;
#pragma unroll
    for (int k8 = 0; k8 < 16; ++k8) {
      half8 v = *(const half8*)&Xt[c * 128 + ((k8 ^ swz) << 3)];
#pragma unroll
      for (int j = 0; j < 8; ++j) s += (float)v[j];
    }
    atomicAdd(&mus[c], s);
  }
}

// ---- U[op] = W[op] @ S[br(op)] ----
__global__ __launch_bounds__(256) void k_varU(
    const float* __restrict__ Wall, const float* __restrict__ Sall,
    float* __restrict__ U, OpList ol) {
  const int op = ol.ops[blockIdx.y];
  const int br = BRTAB[op];
  const float* A = Wall + (size_t)op * 16384;
  const float* B = Sall + (size_t)br * 16384;
  const int d0 = blockIdx.x * 64;
  __shared__ float As[64][32];
  __shared__ float Bs[32][128];
  const int t = threadIdx.x, tr = t >> 5, tc = t & 31;
  float4 acc[8];
#pragma unroll
  for (int i = 0; i < 8; ++i) acc[i] = make_float4(0.f, 0.f, 0.f, 0.f);
  for (int kc = 0; kc < 4; ++kc) {
    const int k0 = kc * 32;
    __syncthreads();
#pragma unroll
    for (int i = 0; i < 2; ++i) {
      int f = t + i * 256;
      int r = f >> 3, kq = f & 7;
      *(float4*)&As[r][kq * 4] = *(const float4*)&A[(d0 + r) * 128 + k0 + kq * 4];
    }
#pragma unroll
    for (int i = 0; i < 4; ++i) {
      int f = t + i * 256;
      int k = f >> 5, c4 = f & 31;
      *(float4*)&Bs[k][c4 * 4] = *(const float4*)&B[(k0 + k) * 128 + c4 * 4];
    }
    __syncthreads();
#pragma unroll
    for (int kq = 0; kq < 8; ++kq) {
      float4 b0 = *(float4*)&Bs[kq * 4 + 0][tc * 4];
      float4 b1 = *(float4*)&Bs[kq * 4 + 1][tc * 4];
      float4 b2 = *(float4*)&Bs[kq * 4 + 2][tc * 4];
      float4 b3 = *(float4*)&Bs[kq * 4 + 3][tc * 4];
#pragma unroll
      for (int i = 0; i < 8; ++i) {
        float4 av = *(float4*)&As[tr * 8 + i][kq * 4];
        acc[i] = f4fma(av.x, b0, acc[i]);
        acc[i] = f4fma(av.y, b1, acc[i]);
        acc[i] = f4fma(av.z, b2, acc[i]);
        acc[i] = f4fma(av.w, b3, acc[i]);
      }
    }
  }
#pragma unroll
  for (int i = 0; i < 8; ++i)
    *(float4*)&U[(size_t)op * 16384 + (d0 + tr * 8 + i) * 128 + tc * 4] = acc[i];
}

// ---- BN fold: scale = g*rsqrt(var+eps), shift = beta - mean_z*scale ----
__global__ void k_bnfinal(OpList ol, const float* __restrict__ Wall,
                          const float* __restrict__ U, const float* __restrict__ mus,
                          const float* __restrict__ gamma, const float* __restrict__ beta,
                          float* __restrict__ scale, float* __restrict__ shift, int n) {
  const int op = ol.ops[blockIdx.x];
  const int br = BRTAB[op];
  const int d = threadIdx.x;
  __shared__ __align__(16) float muL[128];
  const float invN = 1.0f / (float)n;
  muL[d] = mus[br * 128 + d] * invN;
  __syncthreads();
  const float4* Wr = (const float4*)(Wall + (size_t)op * 16384 + d * 128);
  const float4* Ur = (const float4*)(U + (size_t)op * 16384 + d * 128);
  const float4* m4 = (const float4*)muL;
  float q = 0.f, mz = 0.f;
#pragma unroll 8
  for (int j = 0; j < 32; ++j) {
    float4 w = Wr[j], u = Ur[j], m = m4[j];
    q  += w.x * u.x + w.y * u.y + w.z * u.z + w.w * u.w;
    mz += w.x * m.x + w.y * m.y + w.z * m.z + w.w * m.w;
  }
  float var = fmaxf(q * invN - mz * mz, 0.0f);
  float is = 1.0f / sqrtf(var + 1e-5f);
  float scl = gamma[op * 128 + d] * is;
  scale[op * 128 + d] = scl;
  shift[op * 128 + d] = beta[op * 128 + d] - mz * scl;
}

// ---- fused multi-op MFMA GEMM + BN + ReLU + weighted accumulate ----
__global__ __launch_bounds__(256) void k_mix_mfma(
    MixListH ml, const _Float16* __restrict__ Whall, const float* __restrict__ scale,
    const float* __restrict__ shift, const float* __restrict__ wts,
    float* __restrict__ outf, _Float16* __restrict__ outh, int n) {
  __shared__ _Float16 Xs[128 * 128];
  __shared__ _Float16 Ws[128 * 128];
  const int t = threadIdx.x;
  const int lane = t & 63, w = t >> 6;
  const int wr = w >> 1, wc = w & 1;
  const int l15 = lane & 15, l4 = lane >> 4;
  const int row0 = blockIdx.x * 128;
  const int R = wr * 64, Cb = wc * 64;

  f32x4 oacc[4][4];
#pragma unroll
  for (int m = 0; m < 4; ++m)
#pragma unroll
    for (int nn = 0; nn < 4; ++nn) oacc[m][nn] = (f32x4){0.f, 0.f, 0.f, 0.f};

  const _Float16* Xprev = nullptr;
  for (int o = 0; o < ml.nops; ++o) {
    const _Float16* X = ml.X[o];
    const int op = ml.op[o];
    const _Float16* Wp = Whall + (size_t)op * 16384;
    __syncthreads();
    if (X != Xprev) {
      int r = t >> 1, cb = (t & 1) * 8;
      int grow = row0 + r;
      if (grow < n) {
        const half8* src = (const half8*)(X + (size_t)grow * 128);
#pragma unroll
        for (int i = 0; i < 8; ++i) {
          int c = cb + i;
          *(half8*)&Xs[(r << 7) + ((c ^ (r & 15)) << 3)] = src[c];
        }
      } else {
        half8 z = {0, 0, 0, 0, 0, 0, 0, 0};
#pragma unroll
        for (int i = 0; i < 8; ++i) {
          int c = cb + i;
          *(half8*)&Xs[(r << 7) + ((c ^ (r & 15)) << 3)] = z;
        }
      }
      Xprev = X;
    }
    {
      int r = t >> 1, cb = (t & 1) * 8;
      const half8* src = (const half8*)(Wp + (size_t)r * 128);
#pragma unroll
      for (int i = 0; i < 8; ++i) {
        int c = cb + i;
        *(half8*)&Ws[(r << 7) + ((c ^ (r & 15)) << 3)] = src[c];
      }
    }
    __syncthreads();

    f32x4 acc[4][4];
#pragma unroll
    for (int m = 0; m < 4; ++m)
#pragma unroll
      for (int nn = 0; nn < 4; ++nn) acc[m][nn] = (f32x4){0.f, 0.f, 0.f, 0.f};

#pragma unroll
    for (int ks = 0; ks < 4; ++ks) {
      const int chunk = ks * 4 + l4;
      half8 a[4], b[4];
#pragma unroll
      for (int m = 0; m < 4; ++m) {
        int rr = R + m * 16 + l15;
        a[m] = *(const half8*)&Xs[(rr << 7) + ((chunk ^ (rr & 15)) << 3)];
      }
#pragma unroll
      for (int nn = 0; nn < 4; ++nn) {
        int cc = Cb + nn * 16 + l15;
        b[nn] = *(const half8*)&Ws[(cc << 7) + ((chunk ^ (cc & 15)) << 3)];
      }
#pragma unroll
      for (int m = 0; m < 4; ++m)
#pragma unroll
        for (int nn = 0; nn < 4; ++nn)
          acc[m][nn] = __builtin_amdgcn_mfma_f32_16x16x32_f16(a[m], b[nn], acc[m][nn], 0, 0, 0);
    }

    const float wgt = wts[op];
#pragma unroll
    for (int nn = 0; nn < 4; ++nn) {
      int col = Cb + nn * 16 + l15;
      float sc = scale[op * 128 + col];
      float sh = shift[op * 128 + col];
#pragma unroll
      for (int m = 0; m < 4; ++m)
#pragma unroll
        for (int j = 0; j < 4; ++j) {
          float y = fmaxf(fmaf(acc[m][nn][j], sc, sh), 0.f);
          oacc[m][nn][j] = fmaf(wgt, y, oacc[m][nn][j]);
        }
    }
  }

#pragma unroll
  for (int m = 0; m < 4; ++m)
#pragma unroll
    for (int j = 0; j < 4; ++j) {
      int row = row0 + R + m * 16 + l4 * 4 + j;
      if (row < n) {
#pragma unroll
        for (int nn = 0; nn < 4; ++nn) {
          int col = Cb + nn * 16 + l15;
          float v = oacc[m][nn][j];
          outf[(size_t)row * 128 + col] = v;
          if (outh) outh[(size_t)row * 128 + col] = (_Float16)v;
        }
      }
    }
}

extern "C" void kernel_launch(void* const* d_in, const int* in_sizes, int n_in,
                              void* d_out, int out_size, void* d_ws, size_t ws_size,
                              hipStream_t stream) {
  (void)n_in; (void)out_size; (void)ws_size;
  const int*   edge  = (const int*)d_in[0];
  const float* h     = (const float*)d_in[1];
  const float* h_in  = (const float*)d_in[2];
  const float* wts   = (const float*)d_in[3];
  const float* W     = (const float*)d_in[4];
  const float* gamma = (const float*)d_in[6];
  const float* beta  = (const float*)d_in[7];
  float* out = (float*)d_out;

  const int E = in_sizes[0] / 2;
  const int N = in_sizes[1] / 128;
  const int* src = edge;
  const int* dst = edge + E;
  const size_t NF = (size_t)N * 128;

  char* ws = (char*)d_ws;
  size_t off = 0;
  auto carve = [&](size_t bytes) -> void* {
    void* p = ws + off;
    off += (bytes + 511) & ~((size_t)511);
    return p;
  };
  int*      degw  = (int*)carve((size_t)N * 4);
  int*      offw  = (int*)carve((size_t)(N + 1) * 4);
  int*      curw  = (int*)carve((size_t)N * 4);
  int*      csrw  = (int*)carve((size_t)E * 4);
  float*    invw  = (float*)carve((size_t)N * 4);
  float*    Ssum  = (float*)carve((size_t)7 * 16384 * 4);
  float*    musum = (float*)carve((size_t)7 * 128 * 4);
  float*    U     = (float*)carve((size_t)18 * 16384 * 4);
  float*    scl   = (float*)carve((size_t)18 * 128 * 4);
  float*    shf   = (float*)carve((size_t)18 * 128 * 4);
  _Float16* Wh    = (_Float16*)carve((size_t)18 * 16384 * 2);
  _Float16* hb    = (_Float16*)carve(NF * 2);
  _Float16* h_inb = (_Float16*)carve(NF * 2);
  _Float16* agg0b = (_Float16*)carve(NF * 2);
  _Float16* agg1b = (_Float16*)carve(NF * 2);
  _Float16* agg2b = (_Float16*)carve(NF * 2);
  _Float16* s1b   = (_Float16*)carve(NF * 2);
  _Float16* s2b   = (_Float16*)carve(NF * 2);

  float* s1 = out;
  float* s2 = out + NF;
  float* s3 = out + 2 * NF;

  hipMemsetAsync(degw, 0, (size_t)N * 4, stream);
  hipMemsetAsync(Ssum, 0, (size_t)7 * 16384 * 4, stream);
  hipMemsetAsync(musum, 0, (size_t)7 * 128 * 4, stream);

  const int gE    = (E + 255) / 256;
  const int gAgg  = (N + 3) / 4;
  const int gMix  = (N + 127) / 128;
  const int gStat = (N + 127) / 128;

  k_f2h<<<2048, 256, 0, stream>>>(h, hb, (int)(NF / 4));
  k_f2h<<<2048, 256, 0, stream>>>(h_in, h_inb, (int)(NF / 4));
  k_f2h<<<288, 256, 0, stream>>>(W, Wh, 18 * 16384 / 4);

  k_hist<<<gE, 256, 0, stream>>>(dst, degw, E);
  k_scan<<<1, 1024, 0, stream>>>(degw, offw, curw, invw, N);
  k_scatter<<<gE, 256, 0, stream>>>(src, dst, curw, csrw, E);
  k_agg<<<gAgg, 256, 0, stream>>>(hb, csrw, offw, invw, agg0b, N);

  auto stats_batch = [&](const _Float16* X0, int sl0, const _Float16* X1, int sl1,
                         const _Float16* X2, int sl2, int nb) {
    StatsList sl{};
    const _Float16* Xs_[3] = {X0, X1, X2};
    int slots[3] = {sl0, sl1, sl2};
    for (int i = 0; i < nb; ++i) {
      sl.X[i] = Xs_[i];
      sl.S[i] = Ssum + (size_t)slots[i] * 16384;
      sl.mus[i] = musum + (size_t)slots[i] * 128;
    }
    k_stats_mfma<<<dim3(gStat, nb), 256, 0, stream>>>(sl, N);
  };

  // ---- stage 1 ----
  stats_batch(agg0b, 0, hb, 1, h_inb, 2, 3);
  OpList pa{}; { int v[9] = {0,1,2,3,4,5,9,10,11}; for (int i = 0; i < 9; ++i) pa.ops[i] = v[i]; }
  k_varU<<<dim3(2, 9), 256, 0, stream>>>(W, Ssum, U, pa);
  k_bnfinal<<<9, 128, 0, stream>>>(pa, W, U, musum, gamma, beta, scl, shf, N);
  MixListH m1{}; m1.nops = 3;
  m1.X[0] = agg0b; m1.op[0] = 0; m1.X[1] = hb; m1.op[1] = 1; m1.X[2] = h_inb; m1.op[2] = 2;
  k_mix_mfma<<<gMix, 256, 0, stream>>>(m1, Wh, scl, shf, wts, s1, s1b, N);

  // ---- stage 2 ----
  k_agg<<<gAgg, 256, 0, stream>>>(s1b, csrw, offw, invw, agg1b, N);
  stats_batch(s1b, 3, agg1b, 4, nullptr, 0, 2);
  OpList pb{}; { int v[6] = {6,7,8,12,13,14}; for (int i = 0; i < 6; ++i) pb.ops[i] = v[i]; }
  k_varU<<<dim3(2, 6), 256, 0, stream>>>(W, Ssum, U, pb);
  k_bnfinal<<<6, 128, 0, stream>>>(pb, W, U, musum, gamma, beta, scl, shf, N);
  MixListH m2{}; m2.nops = 6;
  m2.X[0] = agg0b; m2.op[0] = 3;
  m2.X[1] = hb;    m2.op[1] = 4;
  m2.X[2] = h_inb; m2.op[2] = 5;
  m2.X[3] = h_inb; m2.op[3] = 8;
  m2.X[4] = agg1b; m2.op[4] = 6;
  m2.X[5] = s1b;   m2.op[5] = 7;
  k_mix_mfma<<<gMix, 256, 0, stream>>>(m2, Wh, scl, shf, wts, s2, s2b, N);

  // ---- stage 3 ----
  k_agg<<<gAgg, 256, 0, stream>>>(s2b, csrw, offw, invw, agg2b, N);
  stats_batch(s2b, 5, agg2b, 6, nullptr, 0, 2);
  OpList pc{}; { int v[3] = {15,16,17}; for (int i = 0; i < 3; ++i) pc.ops[i] = v[i]; }
  k_varU<<<dim3(2, 3), 256, 0, stream>>>(W, Ssum, U, pc);
  k_bnfinal<<<3, 128, 0, stream>>>(pc, W, U, musum, gamma, beta, scl, shf, N);
  MixListH m3{}; m3.nops = 9;
  m3.X[0] = agg0b; m3.op[0] = 9;
  m3.X[1] = hb;    m3.op[1] = 10;
  m3.X[2] = h_inb; m3.op[2] = 11;
  m3.X[3] = h_inb; m3.op[3] = 14;
  m3.X[4] = h_inb; m3.op[4] = 17;
  m3.X[5] = agg1b; m3.op[5] = 12;
  m3.X[6] = s1b;   m3.op[6] = 13;
  m3.X[7] = agg2b; m3.op[7] = 15;
  m3.X[8] = s2b;   m3.op[8] = 16;
  k_mix_mfma<<<gMix, 256, 0, stream>>>(m3, Wh, scl, shf, wts, s3, nullptr, N);
}

// Round 8
// 661.842 us; speedup vs baseline: 4.0936x; 1.1856x over previous
//
#include <hip/hip_runtime.h>
#include <hip/hip_fp16.h>

// branches: 0=agg(h) 1=h 2=h_in 3=s1 4=agg(s1) 5=s2 6=agg(s2)
static __device__ const int BRTAB[18] = {0,1,2, 0,1,2, 4,3,2, 0,1,2, 4,3,2, 6,5,2};

struct OpList   { int ops[9]; };
struct MixListH { const _Float16* X[9]; int op[9]; int nops; };
struct StatsList { const _Float16* X[3]; float* S[3]; float* mus[3]; };

using half8 = __attribute__((ext_vector_type(8))) _Float16;
using half4 = __attribute__((ext_vector_type(4))) _Float16;
using f32x4 = __attribute__((ext_vector_type(4))) float;

__device__ __forceinline__ float4 f4fma(float a, float4 b, float4 c) {
  c.x = fmaf(a, b.x, c.x); c.y = fmaf(a, b.y, c.y);
  c.z = fmaf(a, b.z, c.z); c.w = fmaf(a, b.w, c.w);
  return c;
}

// ---- fp32 -> fp16 conversion ----
__global__ void k_f2h(const float* __restrict__ x, _Float16* __restrict__ y, int n4) {
  for (int i = blockIdx.x * 256 + threadIdx.x; i < n4; i += gridDim.x * 256) {
    float4 v = ((const float4*)x)[i];
    half4 o = { (_Float16)v.x, (_Float16)v.y, (_Float16)v.z, (_Float16)v.w };
    ((half4*)y)[i] = o;
  }
}

// ---- degree histogram ----
__global__ void k_hist(const int* __restrict__ dst, int* __restrict__ deg, int E) {
  int e = blockIdx.x * 256 + threadIdx.x;
  if (e < E) atomicAdd(&deg[dst[e]], 1);
}

// ---- exclusive prefix-sum over degrees (single block) ----
__global__ __launch_bounds__(1024) void k_scan(
    const int* __restrict__ deg, int* __restrict__ off, int* __restrict__ cur,
    float* __restrict__ inv_deg, int n) {
  __shared__ int wsum[16];
  const int t = threadIdx.x, lane = t & 63, wid = t >> 6;
  int running = 0;
  for (int base = 0; base < n; base += 1024) {
    __syncthreads();
    int i = base + t;
    int v = (i < n) ? deg[i] : 0;
    int x = v;
#pragma unroll
    for (int s = 1; s < 64; s <<= 1) {
      int u = __shfl_up(x, (unsigned)s, 64);
      if (lane >= s) x += u;
    }
    if (lane == 63) wsum[wid] = x;
    __syncthreads();
    if (t < 16) {
      int w = wsum[t];
#pragma unroll
      for (int s = 1; s < 16; s <<= 1) {
        int u = __shfl_up(w, (unsigned)s, 16);
        if (t >= s) w += u;
      }
      wsum[t] = w;
    }
    __syncthreads();
    int excl = running + x + ((wid > 0) ? wsum[wid - 1] : 0) - v;
    if (i < n) {
      off[i] = excl; cur[i] = excl;
      inv_deg[i] = 1.0f / fmaxf((float)v, 1.0f);
    }
    running += wsum[15];
  }
  if (t == 0) off[n] = running;
}

// ---- bucket edges by dst ----
__global__ void k_scatter(const int* __restrict__ src, const int* __restrict__ dst,
                          int* __restrict__ cur, int* __restrict__ csr, int E) {
  int e = blockIdx.x * 256 + threadIdx.x;
  if (e < E) {
    int pos = atomicAdd(&cur[dst[e]], 1);
    csr[pos] = src[e];
  }
}

// ---- mean aggregation: wave = 4 edge-groups x 16 lanes, 16B/lane gathers ----
__global__ void k_agg(const _Float16* __restrict__ x, const int* __restrict__ csr,
                      const int* __restrict__ off, const float* __restrict__ inv_deg,
                      _Float16* __restrict__ outb, int n) {
  int node = blockIdx.x * 4 + (threadIdx.x >> 6);
  int lane = threadIdx.x & 63;
  if (node >= n) return;
  const int g = lane >> 4;       // edge-group 0..3
  const int d8 = lane & 15;      // dim-octet
  int e0 = off[node], e1 = off[node + 1];

  float acc[8];
#pragma unroll
  for (int j = 0; j < 8; ++j) acc[j] = 0.f;

  int e = e0 + g;
  int s_next = (e < e1) ? csr[e] : 0;
  while (e < e1) {
    int s = s_next;
    int e2 = e + 4;
    if (e2 < e1) s_next = csr[e2];
    half8 v = *(const half8*)(x + (size_t)s * 128 + d8 * 8);
#pragma unroll
    for (int j = 0; j < 8; ++j) acc[j] += (float)v[j];
    e = e2;
  }
#pragma unroll
  for (int j = 0; j < 8; ++j) {
    acc[j] += __shfl_xor(acc[j], 16, 64);
    acc[j] += __shfl_xor(acc[j], 32, 64);
  }
  if (g == 0) {
    float iv = inv_deg[node];
    half8 o;
#pragma unroll
    for (int j = 0; j < 8; ++j) o[j] = (_Float16)(acc[j] * iv);
    *(half8*)(outb + (size_t)node * 128 + d8 * 8) = o;
  }
}

// ---- MFMA second moments, 512 rows/block (4 chunk-iters), batched branches ----
// S += X_chunk^T @ X_chunk accumulated over 4 chunks, ONE atomic tile at end.
// Col-sums accumulated in registers during staging (c8 = t&15 is invariant).
__global__ __launch_bounds__(256) void k_stats_mfma(
    StatsList sl, int n) {
  const _Float16* __restrict__ X = sl.X[blockIdx.y];
  float* __restrict__ S   = sl.S[blockIdx.y];
  float* __restrict__ mus = sl.mus[blockIdx.y];
  __shared__ _Float16 Xt[128 * 128];  // 32 KB, Xt[c][k] with chunk-XOR swizzle
  __shared__ float mucol[128];
  const int t = threadIdx.x;
  const int lane = t & 63, w = t >> 6;
  const int wr = w >> 1, wc = w & 1;
  const int l15 = lane & 15, l4 = lane >> 4;
  const int base = blockIdx.x * 512;

  if (t < 128) mucol[t] = 0.f;

  f32x4 acc[4][4];
#pragma unroll
  for (int m = 0; m < 4; ++m)
#pragma unroll
    for (int nn = 0; nn < 4; ++nn) acc[m][nn] = (f32x4){0.f, 0.f, 0.f, 0.f};
  float cacc[8];
#pragma unroll
  for (int j = 0; j < 8; ++j) cacc[j] = 0.f;

  for (int ch = 0; ch < 4; ++ch) {
    __syncthreads();  // prior MFMA reads done before LDS overwrite (and mucol init)
#pragma unroll
    for (int jj = 0; jj < 8; ++jj) {
      int flat = t + jj * 256;
      int r = flat >> 4;            // 0..127
      int c8 = flat & 15;           // == t & 15, invariant
      int row = base + ch * 128 + r;
      half8 v = {0, 0, 0, 0, 0, 0, 0, 0};
      if (row < n) v = *(const half8*)(X + (size_t)row * 128 + c8 * 8);
#pragma unroll
      for (int i = 0; i < 8; ++i) {
        int c = c8 * 8 + i;
        int swz = (c & 15) ^ ((c >> 4) & 15);
        Xt[c * 128 + (((r >> 3) ^ swz) << 3) + (r & 7)] = v[i];
        cacc[i] += (float)v[i];
      }
    }
    __syncthreads();

#pragma unroll
    for (int ks = 0; ks < 4; ++ks) {
      const int k8 = ks * 4 + l4;
      half8 a[4], b[4];
#pragma unroll
      for (int m = 0; m < 4; ++m) {
        int c = wr * 64 + m * 16 + l15;
        int swz = (c & 15) ^ ((c >> 4) & 15);
        a[m] = *(const half8*)&Xt[c * 128 + ((k8 ^ swz) << 3)];
      }
#pragma unroll
      for (int nn = 0; nn < 4; ++nn) {
        int c = wc * 64 + nn * 16 + l15;
        int swz = (c & 15) ^ ((c >> 4) & 15);
        b[nn] = *(const half8*)&Xt[c * 128 + ((k8 ^ swz) << 3)];
      }
#pragma unroll
      for (int m = 0; m < 4; ++m)
#pragma unroll
        for (int nn = 0; nn < 4; ++nn)
          acc[m][nn] = __builtin_amdgcn_mfma_f32_16x16x32_f16(a[m], b[nn], acc[m][nn], 0, 0, 0);
    }
  }

  // one atomic tile per block (4x fewer than per-chunk)
#pragma unroll
  for (int m = 0; m < 4; ++m)
#pragma unroll
    for (int nn = 0; nn < 4; ++nn)
#pragma unroll
      for (int j = 0; j < 4; ++j) {
        int rr = wr * 64 + m * 16 + l4 * 4 + j;
        int cc = wc * 64 + nn * 16 + l15;
        atomicAdd(&S[rr * 128 + cc], acc[m][nn][j]);
      }

  // col-sum flush: LDS atomic combine across the 16 row-groups, then global
  {
    int c8 = t & 15;
#pragma unroll
    for (int j = 0; j < 8; ++j) atomicAdd(&mucol[c8 * 8 + j], cacc[j]);
  }
  __syncthreads();
  if (t < 128) atomicAdd(&mus[t], mucol[t]);
}

// ---- U[op] = W[op] @ S[br(op)] ----
__global__ __launch_bounds__(256) void k_varU(
    const float* __restrict__ Wall, const float* __restrict__ Sall,
    float* __restrict__ U, OpList ol) {
  const int op = ol.ops[blockIdx.y];
  const int br = BRTAB[op];
  const float* A = Wall + (size_t)op * 16384;
  const float* B = Sall + (size_t)br * 16384;
  const int d0 = blockIdx.x * 64;
  __shared__ float As[64][32];
  __shared__ float Bs[32][128];
  const int t = threadIdx.x, tr = t >> 5, tc = t & 31;
  float4 acc[8];
#pragma unroll
  for (int i = 0; i < 8; ++i) acc[i] = make_float4(0.f, 0.f, 0.f, 0.f);
  for (int kc = 0; kc < 4; ++kc) {
    const int k0 = kc * 32;
    __syncthreads();
#pragma unroll
    for (int i = 0; i < 2; ++i) {
      int f = t + i * 256;
      int r = f >> 3, kq = f & 7;
      *(float4*)&As[r][kq * 4] = *(const float4*)&A[(d0 + r) * 128 + k0 + kq * 4];
    }
#pragma unroll
    for (int i = 0; i < 4; ++i) {
      int f = t + i * 256;
      int k = f >> 5, c4 = f & 31;
      *(float4*)&Bs[k][c4 * 4] = *(const float4*)&B[(k0 + k) * 128 + c4 * 4];
    }
    __syncthreads();
#pragma unroll
    for (int kq = 0; kq < 8; ++kq) {
      float4 b0 = *(float4*)&Bs[kq * 4 + 0][tc * 4];
      float4 b1 = *(float4*)&Bs[kq * 4 + 1][tc * 4];
      float4 b2 = *(float4*)&Bs[kq * 4 + 2][tc * 4];
      float4 b3 = *(float4*)&Bs[kq * 4 + 3][tc * 4];
#pragma unroll
      for (int i = 0; i < 8; ++i) {
        float4 av = *(float4*)&As[tr * 8 + i][kq * 4];
        acc[i] = f4fma(av.x, b0, acc[i]);
        acc[i] = f4fma(av.y, b1, acc[i]);
        acc[i] = f4fma(av.z, b2, acc[i]);
        acc[i] = f4fma(av.w, b3, acc[i]);
      }
    }
  }
#pragma unroll
  for (int i = 0; i < 8; ++i)
    *(float4*)&U[(size_t)op * 16384 + (d0 + tr * 8 + i) * 128 + tc * 4] = acc[i];
}

// ---- BN fold: scale = g*rsqrt(var+eps), shift = beta - mean_z*scale ----
__global__ void k_bnfinal(OpList ol, const float* __restrict__ Wall,
                          const float* __restrict__ U, const float* __restrict__ mus,
                          const float* __restrict__ gamma, const float* __restrict__ beta,
                          float* __restrict__ scale, float* __restrict__ shift, int n) {
  const int op = ol.ops[blockIdx.x];
  const int br = BRTAB[op];
  const int d = threadIdx.x;
  __shared__ __align__(16) float muL[128];
  const float invN = 1.0f / (float)n;
  muL[d] = mus[br * 128 + d] * invN;
  __syncthreads();
  const float4* Wr = (const float4*)(Wall + (size_t)op * 16384 + d * 128);
  const float4* Ur = (const float4*)(U + (size_t)op * 16384 + d * 128);
  const float4* m4 = (const float4*)muL;
  float q = 0.f, mz = 0.f;
#pragma unroll 8
  for (int j = 0; j < 32; ++j) {
    float4 w = Wr[j], u = Ur[j], m = m4[j];
    q  += w.x * u.x + w.y * u.y + w.z * u.z + w.w * u.w;
    mz += w.x * m.x + w.y * m.y + w.z * m.z + w.w * m.w;
  }
  float var = fmaxf(q * invN - mz * mz, 0.0f);
  float is = 1.0f / sqrtf(var + 1e-5f);
  float scl = gamma[op * 128 + d] * is;
  scale[op * 128 + d] = scl;
  shift[op * 128 + d] = beta[op * 128 + d] - mz * scl;
}

// ---- fused multi-op MFMA GEMM + BN + ReLU + weighted accumulate ----
__global__ __launch_bounds__(256) void k_mix_mfma(
    MixListH ml, const _Float16* __restrict__ Whall, const float* __restrict__ scale,
    const float* __restrict__ shift, const float* __restrict__ wts,
    float* __restrict__ outf, _Float16* __restrict__ outh, int n) {
  __shared__ _Float16 Xs[128 * 128];
  __shared__ _Float16 Ws[128 * 128];
  const int t = threadIdx.x;
  const int lane = t & 63, w = t >> 6;
  const int wr = w >> 1, wc = w & 1;
  const int l15 = lane & 15, l4 = lane >> 4;
  const int row0 = blockIdx.x * 128;
  const int R = wr * 64, Cb = wc * 64;

  f32x4 oacc[4][4];
#pragma unroll
  for (int m = 0; m < 4; ++m)
#pragma unroll
    for (int nn = 0; nn < 4; ++nn) oacc[m][nn] = (f32x4){0.f, 0.f, 0.f, 0.f};

  const _Float16* Xprev = nullptr;
  for (int o = 0; o < ml.nops; ++o) {
    const _Float16* X = ml.X[o];
    const int op = ml.op[o];
    const _Float16* Wp = Whall + (size_t)op * 16384;
    __syncthreads();
    if (X != Xprev) {
      int r = t >> 1, cb = (t & 1) * 8;
      int grow = row0 + r;
      if (grow < n) {
        const half8* src = (const half8*)(X + (size_t)grow * 128);
#pragma unroll
        for (int i = 0; i < 8; ++i) {
          int c = cb + i;
          *(half8*)&Xs[(r << 7) + ((c ^ (r & 15)) << 3)] = src[c];
        }
      } else {
        half8 z = {0, 0, 0, 0, 0, 0, 0, 0};
#pragma unroll
        for (int i = 0; i < 8; ++i) {
          int c = cb + i;
          *(half8*)&Xs[(r << 7) + ((c ^ (r & 15)) << 3)] = z;
        }
      }
      Xprev = X;
    }
    {
      int r = t >> 1, cb = (t & 1) * 8;
      const half8* src = (const half8*)(Wp + (size_t)r * 128);
#pragma unroll
      for (int i = 0; i < 8; ++i) {
        int c = cb + i;
        *(half8*)&Ws[(r << 7) + ((c ^ (r & 15)) << 3)] = src[c];
      }
    }
    __syncthreads();

    f32x4 acc[4][4];
#pragma unroll
    for (int m = 0; m < 4; ++m)
#pragma unroll
      for (int nn = 0; nn < 4; ++nn) acc[m][nn] = (f32x4){0.f, 0.f, 0.f, 0.f};

#pragma unroll
    for (int ks = 0; ks < 4; ++ks) {
      const int chunk = ks * 4 + l4;
      half8 a[4], b[4];
#pragma unroll
      for (int m = 0; m < 4; ++m) {
        int rr = R + m * 16 + l15;
        a[m] = *(const half8*)&Xs[(rr << 7) + ((chunk ^ (rr & 15)) << 3)];
      }
#pragma unroll
      for (int nn = 0; nn < 4; ++nn) {
        int cc = Cb + nn * 16 + l15;
        b[nn] = *(const half8*)&Ws[(cc << 7) + ((chunk ^ (cc & 15)) << 3)];
      }
#pragma unroll
      for (int m = 0; m < 4; ++m)
#pragma unroll
        for (int nn = 0; nn < 4; ++nn)
          acc[m][nn] = __builtin_amdgcn_mfma_f32_16x16x32_f16(a[m], b[nn], acc[m][nn], 0, 0, 0);
    }

    const float wgt = wts[op];
#pragma unroll
    for (int nn = 0; nn < 4; ++nn) {
      int col = Cb + nn * 16 + l15;
      float sc = scale[op * 128 + col];
      float sh = shift[op * 128 + col];
#pragma unroll
      for (int m = 0; m < 4; ++m)
#pragma unroll
        for (int j = 0; j < 4; ++j) {
          float y = fmaxf(fmaf(acc[m][nn][j], sc, sh), 0.f);
          oacc[m][nn][j] = fmaf(wgt, y, oacc[m][nn][j]);
        }
    }
  }

#pragma unroll
  for (int m = 0; m < 4; ++m)
#pragma unroll
    for (int j = 0; j < 4; ++j) {
      int row = row0 + R + m * 16 + l4 * 4 + j;
      if (row < n) {
#pragma unroll
        for (int nn = 0; nn < 4; ++nn) {
          int col = Cb + nn * 16 + l15;
          float v = oacc[m][nn][j];
          outf[(size_t)row * 128 + col] = v;
          if (outh) outh[(size_t)row * 128 + col] = (_Float16)v;
        }
      }
    }
}

extern "C" void kernel_launch(void* const* d_in, const int* in_sizes, int n_in,
                              void* d_out, int out_size, void* d_ws, size_t ws_size,
                              hipStream_t stream) {
  (void)n_in; (void)out_size; (void)ws_size;
  const int*   edge  = (const int*)d_in[0];
  const float* h     = (const float*)d_in[1];
  const float* h_in  = (const float*)d_in[2];
  const float* wts   = (const float*)d_in[3];
  const float* W     = (const float*)d_in[4];
  const float* gamma = (const float*)d_in[6];
  const float* beta  = (const float*)d_in[7];
  float* out = (float*)d_out;

  const int E = in_sizes[0] / 2;
  const int N = in_sizes[1] / 128;
  const int* src = edge;
  const int* dst = edge + E;
  const size_t NF = (size_t)N * 128;

  char* ws = (char*)d_ws;
  size_t off = 0;
  auto carve = [&](size_t bytes) -> void* {
    void* p = ws + off;
    off += (bytes + 511) & ~((size_t)511);
    return p;
  };
  int*      degw  = (int*)carve((size_t)N * 4);
  int*      offw  = (int*)carve((size_t)(N + 1) * 4);
  int*      curw  = (int*)carve((size_t)N * 4);
  int*      csrw  = (int*)carve((size_t)E * 4);
  float*    invw  = (float*)carve((size_t)N * 4);
  float*    Ssum  = (float*)carve((size_t)7 * 16384 * 4);
  float*    musum = (float*)carve((size_t)7 * 128 * 4);
  float*    U     = (float*)carve((size_t)18 * 16384 * 4);
  float*    scl   = (float*)carve((size_t)18 * 128 * 4);
  float*    shf   = (float*)carve((size_t)18 * 128 * 4);
  _Float16* Wh    = (_Float16*)carve((size_t)18 * 16384 * 2);
  _Float16* hb    = (_Float16*)carve(NF * 2);
  _Float16* h_inb = (_Float16*)carve(NF * 2);
  _Float16* agg0b = (_Float16*)carve(NF * 2);
  _Float16* agg1b = (_Float16*)carve(NF * 2);
  _Float16* agg2b = (_Float16*)carve(NF * 2);
  _Float16* s1b   = (_Float16*)carve(NF * 2);
  _Float16* s2b   = (_Float16*)carve(NF * 2);

  float* s1 = out;
  float* s2 = out + NF;
  float* s3 = out + 2 * NF;

  hipMemsetAsync(degw, 0, (size_t)N * 4, stream);
  hipMemsetAsync(Ssum, 0, (size_t)7 * 16384 * 4, stream);
  hipMemsetAsync(musum, 0, (size_t)7 * 128 * 4, stream);

  const int gE    = (E + 255) / 256;
  const int gAgg  = (N + 3) / 4;
  const int gMix  = (N + 127) / 128;
  const int gStat = (N + 511) / 512;

  k_f2h<<<2048, 256, 0, stream>>>(h, hb, (int)(NF / 4));
  k_f2h<<<2048, 256, 0, stream>>>(h_in, h_inb, (int)(NF / 4));
  k_f2h<<<288, 256, 0, stream>>>(W, Wh, 18 * 16384 / 4);

  k_hist<<<gE, 256, 0, stream>>>(dst, degw, E);
  k_scan<<<1, 1024, 0, stream>>>(degw, offw, curw, invw, N);
  k_scatter<<<gE, 256, 0, stream>>>(src, dst, curw, csrw, E);
  k_agg<<<gAgg, 256, 0, stream>>>(hb, csrw, offw, invw, agg0b, N);

  auto stats_batch = [&](const _Float16* X0, int sl0, const _Float16* X1, int sl1,
                         const _Float16* X2, int sl2, int nb) {
    StatsList sl{};
    const _Float16* Xs_[3] = {X0, X1, X2};
    int slots[3] = {sl0, sl1, sl2};
    for (int i = 0; i < nb; ++i) {
      sl.X[i] = Xs_[i];
      sl.S[i] = Ssum + (size_t)slots[i] * 16384;
      sl.mus[i] = musum + (size_t)slots[i] * 128;
    }
    k_stats_mfma<<<dim3(gStat, nb), 256, 0, stream>>>(sl, N);
  };

  // ---- stage 1 ----
  stats_batch(agg0b, 0, hb, 1, h_inb, 2, 3);
  OpList pa{}; { int v[9] = {0,1,2,3,4,5,9,10,11}; for (int i = 0; i < 9; ++i) pa.ops[i] = v[i]; }
  k_varU<<<dim3(2, 9), 256, 0, stream>>>(W, Ssum, U, pa);
  k_bnfinal<<<9, 128, 0, stream>>>(pa, W, U, musum, gamma, beta, scl, shf, N);
  MixListH m1{}; m1.nops = 3;
  m1.X[0] = agg0b; m1.op[0] = 0; m1.X[1] = hb; m1.op[1] = 1; m1.X[2] = h_inb; m1.op[2] = 2;
  k_mix_mfma<<<gMix, 256, 0, stream>>>(m1, Wh, scl, shf, wts, s1, s1b, N);

  // ---- stage 2 ----
  k_agg<<<gAgg, 256, 0, stream>>>(s1b, csrw, offw, invw, agg1b, N);
  stats_batch(s1b, 3, agg1b, 4, nullptr, 0, 2);
  OpList pb{}; { int v[6] = {6,7,8,12,13,14}; for (int i = 0; i < 6; ++i) pb.ops[i] = v[i]; }
  k_varU<<<dim3(2, 6), 256, 0, stream>>>(W, Ssum, U, pb);
  k_bnfinal<<<6, 128, 0, stream>>>(pb, W, U, musum, gamma, beta, scl, shf, N);
  MixListH m2{}; m2.nops = 6;
  m2.X[0] = agg0b; m2.op[0] = 3;
  m2.X[1] = hb;    m2.op[1] = 4;
  m2.X[2] = h_inb; m2.op[2] = 5;
  m2.X[3] = h_inb; m2.op[3] = 8;
  m2.X[4] = agg1b; m2.op[4] = 6;
  m2.X[5] = s1b;   m2.op[5] = 7;
  k_mix_mfma<<<gMix, 256, 0, stream>>>(m2, Wh, scl, shf, wts, s2, s2b, N);

  // ---- stage 3 ----
  k_agg<<<gAgg, 256, 0, stream>>>(s2b, csrw, offw, invw, agg2b, N);
  stats_batch(s2b, 5, agg2b, 6, nullptr, 0, 2);
  OpList pc{}; { int v[3] = {15,16,17}; for (int i = 0; i < 3; ++i) pc.ops[i] = v[i]; }
  k_varU<<<dim3(2, 3), 256, 0, stream>>>(W, Ssum, U, pc);
  k_bnfinal<<<3, 128, 0, stream>>>(pc, W, U, musum, gamma, beta, scl, shf, N);
  MixListH m3{}; m3.nops = 9;
  m3.X[0] = agg0b; m3.op[0] = 9;
  m3.X[1] = hb;    m3.op[1] = 10;
  m3.X[2] = h_inb; m3.op[2] = 11;
  m3.X[3] = h_inb; m3.op[3] = 14;
  m3.X[4] = h_inb; m3.op[4] = 17;
  m3.X[5] = agg1b; m3.op[5] = 12;
  m3.X[6] = s1b;   m3.op[6] = 13;
  m3.X[7] = agg2b; m3.op[7] = 15;
  m3.X[8] = s2b;   m3.op[8] = 16;
  k_mix_mfma<<<gMix, 256, 0, stream>>>(m3, Wh, scl, shf, wts, s3, nullptr, N);
}